// Round 1
// baseline (446.333 us; speedup 1.0000x reference)
//
#include <hip/hip_runtime.h>
#include <math.h>

#define NPTS 2048
#define BATCH 4
#define NG 8
#define KNN_K 16
#define FR_OFF 512     // floats: frames start in ws
#define IDX_OFF 1024   // floats: knn idx (as int) start in ws
#define WOFF_F (IDX_OFF + BATCH * NPTS * KNN_K)  // floats: split weight frags (132096)
#define FLOATMAX 3.402823466e38f

typedef __attribute__((ext_vector_type(8))) short bf16x8;
typedef __attribute__((ext_vector_type(4))) float f32x4;

__device__ inline unsigned short bf16_rne(float x) {
  unsigned u = __float_as_uint(x);
  u += 0x7FFFu + ((u >> 16) & 1u);
  return (unsigned short)(u >> 16);
}
__device__ inline float bf16_f(unsigned short h) {
  return __uint_as_float(((unsigned)h) << 16);
}

// ---------------------------------------------------------------------------
// K1: per-(b,g) stats: wsum, center(3), nmean(3), Rm lower(6)   [unchanged]
// ---------------------------------------------------------------------------
__global__ void stats_kernel(const float* __restrict__ pc, const float* __restrict__ nrm,
                             const float* __restrict__ drw, float* __restrict__ ws) {
  __shared__ float red[256];
  int bg = blockIdx.x;
  int b = bg >> 3, g = bg & 7;
  int t = threadIdx.x;

  float sw = 0.f, sp0 = 0.f, sp1 = 0.f, sp2 = 0.f, sn0 = 0.f, sn1 = 0.f, sn2 = 0.f;
  for (int n = t; n < NPTS; n += 256) {
    float w = drw[((size_t)b * NPTS + n) * NG + g];
    const float* p = pc + ((size_t)b * NPTS + n) * 3;
    const float* nr = nrm + ((size_t)b * NPTS + n) * 3;
    sw += w;
    sp0 += w * p[0]; sp1 += w * p[1]; sp2 += w * p[2];
    sn0 += w * nr[0]; sn1 += w * nr[1]; sn2 += w * nr[2];
  }

  auto blockReduce = [&](float v) -> float {
    red[t] = v; __syncthreads();
    for (int s = 128; s > 0; s >>= 1) {
      if (t < s) red[t] += red[t + s];
      __syncthreads();
    }
    float r = red[0];
    __syncthreads();
    return r;
  };

  float Sw = blockReduce(sw);
  float inv = 1.f / (Sw + 1e-6f);
  float C0 = blockReduce(sp0) * inv;
  float C1 = blockReduce(sp1) * inv;
  float C2 = blockReduce(sp2) * inv;
  float M0 = blockReduce(sn0) * inv;
  float M1 = blockReduce(sn1) * inv;
  float M2 = blockReduce(sn2) * inv;

  float r00 = 0.f, r10 = 0.f, r11 = 0.f, r20 = 0.f, r21 = 0.f, r22 = 0.f;
  for (int n = t; n < NPTS; n += 256) {
    float w = drw[((size_t)b * NPTS + n) * NG + g];
    const float* p = pc + ((size_t)b * NPTS + n) * 3;
    float p0 = p[0] - C0, p1 = p[1] - C1, p2 = p[2] - C2;
    r00 += w * p0 * p0;
    r10 += w * p1 * p0;
    r11 += w * p1 * p1;
    r20 += w * p2 * p0;
    r21 += w * p2 * p1;
    r22 += w * p2 * p2;
  }
  float R00 = blockReduce(r00);
  float R10 = blockReduce(r10);
  float R11 = blockReduce(r11);
  float R20 = blockReduce(r20);
  float R21 = blockReduce(r21);
  float R22 = blockReduce(r22);

  if (t == 0) {
    float* st = ws + bg * 16;
    st[0] = Sw;
    st[1] = C0; st[2] = C1; st[3] = C2;
    st[4] = M0; st[5] = M1; st[6] = M2;
    st[7] = R00; st[8] = R10; st[9] = R11; st[10] = R20; st[11] = R21; st[12] = R22;
  }
}

// ---------------------------------------------------------------------------
// K2: eigh of 3x3 symmetric, LAPACK ssyevd-faithful               [unchanged]
// ---------------------------------------------------------------------------
__device__ inline float slapy2f(float x, float y) {
  float ax = fabsf(x), ay = fabsf(y);
  float w = fmaxf(ax, ay), z = fminf(ax, ay);
  if (z == 0.f) return w;
  float q = z / w;
  return w * sqrtf(1.f + q * q);
}

__device__ inline void slartgf(float f, float g, float& c, float& s, float& r) {
  if (g == 0.f) { c = 1.f; s = 0.f; r = f; }
  else if (f == 0.f) { c = 0.f; s = (g >= 0.f) ? 1.f : -1.f; r = fabsf(g); }
  else {
    float d = sqrtf(f * f + g * g);
    c = fabsf(f) / d;
    r = (f >= 0.f) ? d : -d;
    s = g / r;
  }
}

__device__ void slaev2f(float a, float b, float c, float& rt1, float& rt2, float& cs1, float& sn1) {
  float sm = a + c, df = a - c, adf = fabsf(df), tb = b + b, ab = fabsf(tb);
  float acmx, acmn;
  if (fabsf(a) > fabsf(c)) { acmx = a; acmn = c; } else { acmx = c; acmn = a; }
  float rt;
  if (adf > ab) { float t = ab / adf; rt = adf * sqrtf(1.f + t * t); }
  else if (adf < ab) { float t = adf / ab; rt = ab * sqrtf(1.f + t * t); }
  else rt = ab * sqrtf(2.f);
  int sgn1;
  if (sm < 0.f) { rt1 = 0.5f * (sm - rt); sgn1 = -1; rt2 = (acmx / rt1) * acmn - (b / rt1) * b; }
  else if (sm > 0.f) { rt1 = 0.5f * (sm + rt); sgn1 = 1; rt2 = (acmx / rt1) * acmn - (b / rt1) * b; }
  else { rt1 = 0.5f * rt; rt2 = -0.5f * rt; sgn1 = 1; }
  float cs; int sgn2;
  if (df >= 0.f) { cs = df + rt; sgn2 = 1; } else { cs = df - rt; sgn2 = -1; }
  float acs = fabsf(cs);
  if (acs > ab) {
    float ct = -tb / cs;
    sn1 = 1.f / sqrtf(1.f + ct * ct);
    cs1 = ct * sn1;
  } else {
    if (ab == 0.f) { cs1 = 1.f; sn1 = 0.f; }
    else {
      float tn = -cs / tb;
      cs1 = 1.f / sqrtf(1.f + tn * tn);
      sn1 = tn * cs1;
    }
  }
  if (sgn1 == sgn2) { float tn = cs1; cs1 = -sn1; sn1 = tn; }
}

__device__ void steqr3(float d[3], float e[2], float Z[3][3]) {
  const float eps = 5.9604645e-08f;
  const float eps2 = eps * eps;
  const float safmin = 1.17549435e-38f;
  const int nmaxit = 90;
  const int n = 3;
  int jtot = 0;
  int l1 = 0;
  while (l1 <= n - 1) {
    if (l1 > 0) e[l1 - 1] = 0.f;
    int m;
    for (m = l1; m <= n - 2; m++) {
      float tst = fabsf(e[m]);
      if (tst == 0.f) break;
      if (tst <= (sqrtf(fabsf(d[m])) * sqrtf(fabsf(d[m + 1]))) * eps) { e[m] = 0.f; break; }
    }
    int l = l1, lend = m;
    l1 = m + 1;
    if (lend == l) continue;
    if (fabsf(d[lend]) < fabsf(d[l])) { int tmp = l; l = lend; lend = tmp; }
    if (lend > l) {
      for (;;) {
        int mm = lend;
        if (l != lend) {
          for (mm = l; mm <= lend - 1; mm++) {
            float tst = e[mm] * e[mm];
            if (tst <= eps2 * fabsf(d[mm]) * fabsf(d[mm + 1]) + safmin) break;
          }
        }
        if (mm < lend) e[mm] = 0.f;
        float p = d[l];
        if (mm == l) {
          d[l] = p; l++;
          if (l <= lend) continue; else break;
        }
        if (mm == l + 1) {
          float rt1, rt2, c, s;
          slaev2f(d[l], e[l], d[l + 1], rt1, rt2, c, s);
          #pragma unroll
          for (int i = 0; i < 3; i++) {
            float tp = Z[i][l + 1];
            Z[i][l + 1] = c * tp - s * Z[i][l];
            Z[i][l] = s * tp + c * Z[i][l];
          }
          d[l] = rt1; d[l + 1] = rt2; e[l] = 0.f;
          l += 2;
          if (l <= lend) continue; else break;
        }
        if (jtot == nmaxit) break;
        jtot++;
        float g = (d[l + 1] - p) / (2.f * e[l]);
        float r = slapy2f(g, 1.f);
        g = d[mm] - p + e[l] / (g + copysignf(r, g));
        float s = 1.f, c = 1.f;
        p = 0.f;
        float cs[2], sn[2];
        for (int i = mm - 1; i >= l; i--) {
          float f = s * e[i];
          float bb = c * e[i];
          slartgf(g, f, c, s, r);
          if (i != mm - 1) e[i + 1] = r;
          g = d[i + 1] - p;
          r = (d[i] - g) * s + 2.f * c * bb;
          p = s * r;
          d[i + 1] = g + p;
          g = c * r - bb;
          cs[i] = c; sn[i] = -s;
        }
        for (int jj = mm - l - 1; jj >= 0; jj--) {
          float c_ = cs[l + jj], s_ = sn[l + jj];
          #pragma unroll
          for (int i = 0; i < 3; i++) {
            float tp = Z[i][l + jj + 1];
            Z[i][l + jj + 1] = c_ * tp - s_ * Z[i][l + jj];
            Z[i][l + jj] = s_ * tp + c_ * Z[i][l + jj];
          }
        }
        d[l] -= p;
        e[l] = g;
      }
    } else {
      for (;;) {
        int mm = lend;
        if (l != lend) {
          for (mm = l; mm >= lend + 1; mm--) {
            float tst = e[mm - 1] * e[mm - 1];
            if (tst <= eps2 * fabsf(d[mm]) * fabsf(d[mm - 1]) + safmin) break;
          }
        }
        if (mm > lend) e[mm - 1] = 0.f;
        float p = d[l];
        if (mm == l) {
          d[l] = p; l--;
          if (l >= lend) continue; else break;
        }
        if (mm == l - 1) {
          float rt1, rt2, c, s;
          slaev2f(d[l - 1], e[l - 1], d[l], rt1, rt2, c, s);
          #pragma unroll
          for (int i = 0; i < 3; i++) {
            float tp = Z[i][l];
            Z[i][l] = c * tp - s * Z[i][l - 1];
            Z[i][l - 1] = s * tp + c * Z[i][l - 1];
          }
          d[l - 1] = rt1; d[l] = rt2; e[l - 1] = 0.f;
          l -= 2;
          if (l >= lend) continue; else break;
        }
        if (jtot == nmaxit) break;
        jtot++;
        float g = (d[l - 1] - p) / (2.f * e[l - 1]);
        float r = slapy2f(g, 1.f);
        g = d[mm] - p + e[l - 1] / (g + copysignf(r, g));
        float s = 1.f, c = 1.f;
        p = 0.f;
        float cs[2], sn[2];
        for (int i = mm; i <= l - 1; i++) {
          float f = s * e[i];
          float bb = c * e[i];
          slartgf(g, f, c, s, r);
          if (i != mm) e[i - 1] = r;
          g = d[i] - p;
          r = (d[i + 1] - g) * s + 2.f * c * bb;
          p = s * r;
          d[i] = g + p;
          g = c * r - bb;
          cs[i] = c; sn[i] = s;
        }
        for (int jj = 0; jj <= l - mm - 1; jj++) {
          float c_ = cs[mm + jj], s_ = sn[mm + jj];
          #pragma unroll
          for (int i = 0; i < 3; i++) {
            float tp = Z[i][mm + jj + 1];
            Z[i][mm + jj + 1] = c_ * tp - s_ * Z[i][mm + jj];
            Z[i][mm + jj] = s_ * tp + c_ * Z[i][mm + jj];
          }
        }
        d[l] -= p;
        e[l - 1] = g;
      }
    }
  }
  for (int ii = 1; ii < 3; ii++) {
    int i = ii - 1, k = i;
    float p = d[i];
    for (int j = ii; j < 3; j++) if (d[j] < p) { k = j; p = d[j]; }
    if (k != i) {
      d[k] = d[i]; d[i] = p;
      for (int r2 = 0; r2 < 3; r2++) {
        float tp = Z[r2][i]; Z[r2][i] = Z[r2][k]; Z[r2][k] = tp;
      }
    }
  }
}

__global__ void eigh_kernel(float* __restrict__ ws) {
  if (threadIdx.x != 0) return;
  int id = blockIdx.x;
  const float* st = ws + id * 16;
  float A00 = st[7], A10 = st[8], A11 = st[9], A20 = st[10], A21 = st[11], A22 = st[12];

  float d[3], e[2];
  float tau = 0.f, u2 = 0.f;
  d[0] = A00;
  float alpha = A10, x31 = A20;
  if (x31 == 0.f) {
    tau = 0.f; u2 = 0.f;
    d[1] = A11; d[2] = A22; e[0] = alpha; e[1] = A21;
  } else {
    float nrm = slapy2f(alpha, fabsf(x31));
    float beta = (alpha >= 0.f) ? -nrm : nrm;
    tau = (beta - alpha) / beta;
    u2 = (1.f / (alpha - beta)) * x31;
    float x1 = tau * (A11 + A21 * u2);
    float x2 = tau * (A21 + A22 * u2);
    float al = -0.5f * tau * (x1 + x2 * u2);
    x1 = x1 + al;
    x2 = x2 + al * u2;
    d[1] = A11 - 2.f * x1;
    e[1] = A21 - (u2 * x1 + x2);
    d[2] = A22 - 2.f * (u2 * x2);
    e[0] = beta;
  }

  float Z[3][3] = {{1.f, 0.f, 0.f}, {0.f, 1.f, 0.f}, {0.f, 0.f, 1.f}};
  steqr3(d, e, Z);

  if (tau != 0.f) {
    for (int j = 0; j < 3; j++) {
      float w = Z[1][j] + u2 * Z[2][j];
      float tw = tau * w;
      Z[1][j] -= tw;
      Z[2][j] -= tw * u2;
    }
  }
  float* fr = ws + FR_OFF + id * 9;
  for (int dd = 0; dd < 3; dd++)
    for (int ee = 0; ee < 3; ee++)
      fr[dd * 3 + ee] = Z[dd][ee];
}

// ---------------------------------------------------------------------------
// K3: soft-weighted kNN, wave-per-query, registers-only selection. [unchanged]
// ---------------------------------------------------------------------------
__global__ __launch_bounds__(256, 4) void knn_kernel(const float* __restrict__ pc,
                                                     const float* __restrict__ drw,
                                                     int* __restrict__ idxout) {
  int t = threadIdx.x;
  int lane = t & 63;
  int q = blockIdx.x * 4 + (t >> 6);
  int b = q >> 11;
  int n = q & (NPTS - 1);

  const float* qp = pc + ((size_t)b * NPTS + n) * 3;
  float q0 = qp[0], q1 = qp[1], q2 = qp[2];
  const float4* qw4 = (const float4*)(drw + ((size_t)b * NPTS + n) * NG);
  float4 qa = qw4[0], qb = qw4[1];

  float d[32];
  #pragma unroll
  for (int j = 0; j < 32; j++) {
    int m = j * 64 + lane;
    const float4* mw4 = (const float4*)(drw + ((size_t)b * NPTS + m) * NG);
    float4 ma = mw4[0], mb = mw4[1];
    float ww = qa.x * ma.x + qa.y * ma.y + qa.z * ma.z + qa.w * ma.w
             + qb.x * mb.x + qb.y * mb.y + qb.z * mb.z + qb.w * mb.w;
    const float* mp = pc + ((size_t)b * NPTS + m) * 3;
    float dx = q0 - mp[0], dy = q1 - mp[1], dz = q2 - mp[2];
    float sq = dx * dx + dy * dy + dz * dz;
    d[j] = ww * sq + (1.f - ww) * 1000.f;
    if ((j & 3) == 3) __builtin_amdgcn_sched_barrier(0);
  }

  int myres = 0;
  #pragma unroll 1
  for (int r = 0; r < KNN_K; r++) {
    float bd = d[0];
    int bj = 0;
    #pragma unroll
    for (int j = 1; j < 32; j++) {
      if (d[j] < bd) { bd = d[j]; bj = j; }
    }
    int gm = bj * 64 + lane;
    #pragma unroll
    for (int s = 1; s < 64; s <<= 1) {
      float od = __shfl_xor(bd, s, 64);
      int om = __shfl_xor(gm, s, 64);
      if (od < bd || (od == bd && om < gm)) { bd = od; gm = om; }
    }
    if (lane == r) myres = gm;
    int ls = gm & 63, js = gm >> 6;
    if (lane == ls) {
      #pragma unroll
      for (int j = 0; j < 32; j++) {
        if (j == js) d[j] = FLOATMAX;
      }
    }
  }
  if (lane < KNN_K) idxout[(size_t)q * KNN_K + lane] = myres;
}

// ---------------------------------------------------------------------------
// K3.5: weight prep — split fp32 W into (hi,lo) bf16 MFMA B-fragments in ws.
// Frag-pair p (1KB hi + 1KB lo): lane holds B[k = kt*32 + (lane>>4)*8 + i]
// [col = nt*16 + (lane&15)], zero-padded for k >= CIN. One-time, trivial cost.
// ---------------------------------------------------------------------------
__global__ void wprep_kernel(const float* __restrict__ W1, const float* __restrict__ W2,
                             const float* __restrict__ W3, const float* __restrict__ W4,
                             const float* __restrict__ W5, float* __restrict__ ws) {
  const int FB[5] = {0, 4, 7, 15, 25};
  const int NTs[5] = {2, 3, 4, 5, 6};
  const int CINs[5] = {51, 32, 48, 64, 80};
  const int COUTs[5] = {32, 48, 64, 80, 96};
  const float* Ws[5] = {W1, W2, W3, W4, W5};

  int fp = blockIdx.x;            // 0..42
  int layer = 0;
  while (layer < 4 && fp >= FB[layer + 1]) layer++;
  int rel = fp - FB[layer];
  int kt = rel / NTs[layer], nt = rel % NTs[layer];
  int lane = threadIdx.x;         // 0..63
  int c = nt * 16 + (lane & 15);
  int q = lane >> 4;
  int cin = CINs[layer], cout = COUTs[layer];
  const float* W = Ws[layer];

  unsigned short* wb = (unsigned short*)(ws + WOFF_F);
  unsigned short* dH = wb + fp * 1024 + lane * 8;
  unsigned short* dL = dH + 512;
  for (int i = 0; i < 8; i++) {
    int k = kt * 32 + q * 8 + i;
    float w = (k < cin) ? W[(size_t)k * cout + c] : 0.f;
    unsigned short hb = bf16_rne(w);
    dH[i] = hb;
    dL[i] = bf16_rne(w - bf16_f(hb));
  }
}

// ---------------------------------------------------------------------------
// K4: feature build + 5-layer MLP on the MATRIX pipe (split-bf16 MFMA).
// Block = 64 rows (8 n x 8 ops); each wave owns one 16-row M-tile end-to-end.
// Activations ping-pong through LDS bf16 hi/lo planes, fixed stride 104
// (208B rows -> <=2-way LDS bank aliasing, free per m136). fp32 precision
// recovered via 3 products hh + hl + lh with RNE splits (err ~2^-17 rel).
// A/B k-permutation is self-consistent (cancels); C/D layout per m89/m91.
// ---------------------------------------------------------------------------
#define ASTRIDE 104

template <int CIN, int COUT, int FB>
__device__ inline void mfma_layer(const unsigned short* __restrict__ wfr,
                                  const unsigned short* inH, const unsigned short* inL,
                                  unsigned short* outH, unsigned short* outL,
                                  const float* __restrict__ Bb, const float* __restrict__ Ss,
                                  const float* __restrict__ Oo, int lane, int wv) {
  constexpr int KT = (CIN + 31) / 32;
  constexpr int NT = COUT / 16;
  int r = lane & 15, q = lane >> 4;
  int arow = (wv * 16 + r) * ASTRIDE;

  f32x4 acc[NT];
  #pragma unroll
  for (int i = 0; i < NT; i++) acc[i] = (f32x4){0.f, 0.f, 0.f, 0.f};

  #pragma unroll
  for (int kt = 0; kt < KT; kt++) {
    bf16x8 ah = *(const bf16x8*)(inH + arow + kt * 32 + q * 8);
    bf16x8 al = *(const bf16x8*)(inL + arow + kt * 32 + q * 8);
    #pragma unroll
    for (int nt = 0; nt < NT; nt++) {
      int fid = FB + kt * NT + nt;
      bf16x8 bh = *(const bf16x8*)(wfr + fid * 1024 + lane * 8);
      bf16x8 bl = *(const bf16x8*)(wfr + fid * 1024 + 512 + lane * 8);
      acc[nt] = __builtin_amdgcn_mfma_f32_16x16x32_bf16(ah, bh, acc[nt], 0, 0, 0);
      acc[nt] = __builtin_amdgcn_mfma_f32_16x16x32_bf16(ah, bl, acc[nt], 0, 0, 0);
      acc[nt] = __builtin_amdgcn_mfma_f32_16x16x32_bf16(al, bh, acc[nt], 0, 0, 0);
    }
  }

  #pragma unroll
  for (int nt = 0; nt < NT; nt++) {
    int c = nt * 16 + r;
    float bb = Bb[c], ss = Ss[c], oo = Oo[c];
    #pragma unroll
    for (int j = 0; j < 4; j++) {
      float h = fmaxf(fmaf(acc[nt][j] + bb, ss, oo), 0.f);
      unsigned short hb = bf16_rne(h);
      int rr = (wv * 16 + q * 4 + j) * ASTRIDE + c;
      outH[rr] = hb;
      outL[rr] = bf16_rne(h - bf16_f(hb));
    }
  }
}

__global__ __launch_bounds__(256) void mlp_kernel(
    const float* __restrict__ pc, const float* __restrict__ nrm, const float* __restrict__ drw,
    const int* __restrict__ kidx, const float* __restrict__ ws,
    const float* __restrict__ B1, const float* __restrict__ S1, const float* __restrict__ O1,
    const float* __restrict__ B2, const float* __restrict__ S2, const float* __restrict__ O2,
    const float* __restrict__ B3, const float* __restrict__ S3, const float* __restrict__ O3,
    const float* __restrict__ B4, const float* __restrict__ S4, const float* __restrict__ O4,
    const float* __restrict__ B5, const float* __restrict__ S5, const float* __restrict__ O5,
    float* __restrict__ out) {
  __shared__ __align__(16) unsigned short actH[2][64 * ASTRIDE];
  __shared__ __align__(16) unsigned short actL[2][64 * ASTRIDE];
  __shared__ float sfr[9], sc[3], snm[3], swn[8];

  int t = threadIdx.x;
  int bi = blockIdx.x;
  int b = bi >> 11;
  int g = (bi >> 8) & 7;
  int n0 = (bi & 255) << 3;
  int bg = b * 8 + g;

  if (t < 9) sfr[t] = ws[FR_OFF + bg * 9 + t];
  else if (t >= 16 && t < 19) sc[t - 16] = ws[bg * 16 + 1 + (t - 16)];
  else if (t >= 32 && t < 35) snm[t - 32] = ws[bg * 16 + 4 + (t - 32)];
  else if (t >= 64 && t < 72) swn[t - 64] = drw[((size_t)b * NPTS + n0 + (t - 64)) * NG + g];

  // zero both act buffers (guarantees finite k-pad; weight pads are 0 anyway)
  {
    unsigned* zH = (unsigned*)actH;
    unsigned* zL = (unsigned*)actL;
    #pragma unroll
    for (int z = 0; z < 26; z++) {   // 26*256 = 6656 = 2*64*104/2 words each
      zH[z * 256 + t] = 0u;
      zL[z * 256 + t] = 0u;
    }
  }
  __syncthreads();

  // ---- feature fill into buf0: base value once, 8 sign-op variants via bf16
  // sign-bit XOR (exact under RNE). f1: feat = 3*kk+e; f2: feat = 48+e.
  if (t < 128) {
    int i = t >> 4, kk = t & 15;
    int n = n0 + i;
    int id = kidx[((size_t)b * NPTS + n) * KNN_K + kk];
    const float* p = pc + ((size_t)b * NPTS + id) * 3;
    float w = swn[i];
    float v0 = w * (p[0] - sc[0]);
    float v1 = w * (p[1] - sc[1]);
    float v2 = w * (p[2] - sc[2]);
    #pragma unroll
    for (int e = 0; e < 3; e++) {
      float gv = v0 * sfr[e] + v1 * sfr[3 + e] + v2 * sfr[6 + e];
      unsigned short hb = bf16_rne(gv);
      unsigned short lb = bf16_rne(gv - bf16_f(hb));
      int f = 3 * kk + e;
      #pragma unroll
      for (int op = 0; op < 8; op++) {
        int sb = (e == 0) ? (op >> 2) : (e == 1) ? (op >> 1) : op;
        unsigned short sgn = (unsigned short)((sb & 1) << 15);
        int rr = (i * 8 + op) * ASTRIDE + f;
        actH[0][rr] = (unsigned short)(hb ^ sgn);
        actL[0][rr] = (unsigned short)(lb ^ sgn);
      }
    }
  } else if (t < 136) {
    int i = t - 128;
    int n = n0 + i;
    float w = swn[i];
    const float* nr = nrm + ((size_t)b * NPTS + n) * 3;
    float v0 = nr[0] * w + (1.f - w) * snm[0];
    float v1 = nr[1] * w + (1.f - w) * snm[1];
    float v2 = nr[2] * w + (1.f - w) * snm[2];
    #pragma unroll
    for (int e = 0; e < 3; e++) {
      float gv = v0 * sfr[e] + v1 * sfr[3 + e] + v2 * sfr[6 + e];
      unsigned short hb = bf16_rne(gv);
      unsigned short lb = bf16_rne(gv - bf16_f(hb));
      int f = 48 + e;
      #pragma unroll
      for (int op = 0; op < 8; op++) {
        int sb = (e == 0) ? (op >> 2) : (e == 1) ? (op >> 1) : op;
        unsigned short sgn = (unsigned short)((sb & 1) << 15);
        int rr = (i * 8 + op) * ASTRIDE + f;
        actH[0][rr] = (unsigned short)(hb ^ sgn);
        actL[0][rr] = (unsigned short)(lb ^ sgn);
      }
    }
  }
  __syncthreads();

  const unsigned short* wfr = (const unsigned short*)(ws + WOFF_F);
  int lane = t & 63;
  int wv = t >> 6;

  mfma_layer<51, 32, 0>(wfr, actH[0], actL[0], actH[1], actL[1], B1, S1, O1, lane, wv);
  __syncthreads();
  mfma_layer<32, 48, 4>(wfr, actH[1], actL[1], actH[0], actL[0], B2, S2, O2, lane, wv);
  __syncthreads();
  mfma_layer<48, 64, 7>(wfr, actH[0], actL[0], actH[1], actL[1], B3, S3, O3, lane, wv);
  __syncthreads();
  mfma_layer<64, 80, 15>(wfr, actH[1], actL[1], actH[0], actL[0], B4, S4, O4, lane, wv);
  __syncthreads();

  // ---- final layer 80 -> 96: MFMA then masked global store (16-lane groups
  // write 64B contiguous).
  {
    constexpr int KT = 3, NT = 6, FB = 25;
    int r = lane & 15, q = lane >> 4;
    int arow = (wv * 16 + r) * ASTRIDE;
    f32x4 acc[NT];
    #pragma unroll
    for (int i = 0; i < NT; i++) acc[i] = (f32x4){0.f, 0.f, 0.f, 0.f};
    #pragma unroll
    for (int kt = 0; kt < KT; kt++) {
      bf16x8 ah = *(const bf16x8*)(actH[0] + arow + kt * 32 + q * 8);
      bf16x8 al = *(const bf16x8*)(actL[0] + arow + kt * 32 + q * 8);
      #pragma unroll
      for (int nt = 0; nt < NT; nt++) {
        int fid = FB + kt * NT + nt;
        bf16x8 bh = *(const bf16x8*)(wfr + fid * 1024 + lane * 8);
        bf16x8 bl = *(const bf16x8*)(wfr + fid * 1024 + 512 + lane * 8);
        acc[nt] = __builtin_amdgcn_mfma_f32_16x16x32_bf16(ah, bh, acc[nt], 0, 0, 0);
        acc[nt] = __builtin_amdgcn_mfma_f32_16x16x32_bf16(ah, bl, acc[nt], 0, 0, 0);
        acc[nt] = __builtin_amdgcn_mfma_f32_16x16x32_bf16(al, bh, acc[nt], 0, 0, 0);
      }
    }
    #pragma unroll
    for (int nt = 0; nt < NT; nt++) {
      int c = nt * 16 + r;
      float bb = B5[c], ss = S5[c], oo = O5[c];
      #pragma unroll
      for (int j = 0; j < 4; j++) {
        int rr = wv * 16 + q * 4 + j;
        int i = rr >> 3, op = rr & 7;
        int n = n0 + i;
        float h = fmaxf(fmaf(acc[nt][j] + bb, ss, oo), 0.f);
        float hv = (swn[i] >= 0.1f) ? h : 0.f;
        out[((((size_t)(b * 8 + op)) * NG + g) * NPTS + n) * 96 + c] = hv;
      }
    }
  }
}

// ---------------------------------------------------------------------------
extern "C" void kernel_launch(void* const* d_in, const int* in_sizes, int n_in,
                              void* d_out, int out_size, void* d_ws, size_t ws_size,
                              hipStream_t stream) {
  const float* pc = (const float*)d_in[0];
  const float* nrm = (const float*)d_in[1];
  const float* drw = (const float*)d_in[2];
  const float* W1 = (const float*)d_in[3];
  const float* B1 = (const float*)d_in[4];
  const float* S1 = (const float*)d_in[5];
  const float* O1 = (const float*)d_in[6];
  const float* W2 = (const float*)d_in[7];
  const float* B2 = (const float*)d_in[8];
  const float* S2 = (const float*)d_in[9];
  const float* O2 = (const float*)d_in[10];
  const float* W3 = (const float*)d_in[11];
  const float* B3 = (const float*)d_in[12];
  const float* S3 = (const float*)d_in[13];
  const float* O3 = (const float*)d_in[14];
  const float* W4 = (const float*)d_in[15];
  const float* B4 = (const float*)d_in[16];
  const float* S4 = (const float*)d_in[17];
  const float* O4 = (const float*)d_in[18];
  const float* W5 = (const float*)d_in[19];
  const float* B5 = (const float*)d_in[20];
  const float* S5 = (const float*)d_in[21];
  const float* O5 = (const float*)d_in[22];
  float* out = (float*)d_out;
  float* wsf = (float*)d_ws;
  int* idxw = (int*)(wsf + IDX_OFF);

  wprep_kernel<<<43, 64, 0, stream>>>(W1, W2, W3, W4, W5, wsf);
  stats_kernel<<<32, 256, 0, stream>>>(pc, nrm, drw, wsf);
  eigh_kernel<<<32, 64, 0, stream>>>(wsf);
  knn_kernel<<<BATCH * NPTS / 4, 256, 0, stream>>>(pc, drw, idxw);
  mlp_kernel<<<BATCH * NG * (NPTS / 8), 256, 0, stream>>>(
      pc, nrm, drw, idxw, wsf,
      B1, S1, O1, B2, S2, O2, B3, S3, O3,
      B4, S4, O4, B5, S5, O5, out);
}

// Round 2
// 389.114 us; speedup vs baseline: 1.1470x; 1.1470x over previous
//
#include <hip/hip_runtime.h>
#include <math.h>

#define NPTS 2048
#define BATCH 4
#define NG 8
#define KNN_K 16
#define FR_OFF 512     // floats: frames start in ws
#define IDX_OFF 1024   // floats: knn idx (as int) start in ws
#define WOFF_F (IDX_OFF + BATCH * NPTS * KNN_K)  // floats: split weight frags (132096)
#define FLOATMAX 3.402823466e38f

typedef __attribute__((ext_vector_type(8))) short bf16x8;
typedef __attribute__((ext_vector_type(4))) float f32x4;

__device__ inline unsigned short bf16_rne(float x) {
  unsigned u = __float_as_uint(x);
  u += 0x7FFFu + ((u >> 16) & 1u);
  return (unsigned short)(u >> 16);
}
__device__ inline float bf16_f(unsigned short h) {
  return __uint_as_float(((unsigned)h) << 16);
}

// ---------------------------------------------------------------------------
// eigh of 3x3 symmetric, LAPACK ssyevd-faithful (sytrd + steqr + ormtr)
// ---------------------------------------------------------------------------
__device__ inline float slapy2f(float x, float y) {
  float ax = fabsf(x), ay = fabsf(y);
  float w = fmaxf(ax, ay), z = fminf(ax, ay);
  if (z == 0.f) return w;
  float q = z / w;
  return w * sqrtf(1.f + q * q);
}

__device__ inline void slartgf(float f, float g, float& c, float& s, float& r) {
  if (g == 0.f) { c = 1.f; s = 0.f; r = f; }
  else if (f == 0.f) { c = 0.f; s = (g >= 0.f) ? 1.f : -1.f; r = fabsf(g); }
  else {
    float d = sqrtf(f * f + g * g);
    c = fabsf(f) / d;
    r = (f >= 0.f) ? d : -d;
    s = g / r;
  }
}

__device__ void slaev2f(float a, float b, float c, float& rt1, float& rt2, float& cs1, float& sn1) {
  float sm = a + c, df = a - c, adf = fabsf(df), tb = b + b, ab = fabsf(tb);
  float acmx, acmn;
  if (fabsf(a) > fabsf(c)) { acmx = a; acmn = c; } else { acmx = c; acmn = a; }
  float rt;
  if (adf > ab) { float t = ab / adf; rt = adf * sqrtf(1.f + t * t); }
  else if (adf < ab) { float t = adf / ab; rt = ab * sqrtf(1.f + t * t); }
  else rt = ab * sqrtf(2.f);
  int sgn1;
  if (sm < 0.f) { rt1 = 0.5f * (sm - rt); sgn1 = -1; rt2 = (acmx / rt1) * acmn - (b / rt1) * b; }
  else if (sm > 0.f) { rt1 = 0.5f * (sm + rt); sgn1 = 1; rt2 = (acmx / rt1) * acmn - (b / rt1) * b; }
  else { rt1 = 0.5f * rt; rt2 = -0.5f * rt; sgn1 = 1; }
  float cs; int sgn2;
  if (df >= 0.f) { cs = df + rt; sgn2 = 1; } else { cs = df - rt; sgn2 = -1; }
  float acs = fabsf(cs);
  if (acs > ab) {
    float ct = -tb / cs;
    sn1 = 1.f / sqrtf(1.f + ct * ct);
    cs1 = ct * sn1;
  } else {
    if (ab == 0.f) { cs1 = 1.f; sn1 = 0.f; }
    else {
      float tn = -cs / tb;
      cs1 = 1.f / sqrtf(1.f + tn * tn);
      sn1 = tn * cs1;
    }
  }
  if (sgn1 == sgn2) { float tn = cs1; cs1 = -sn1; sn1 = tn; }
}

__device__ void steqr3(float d[3], float e[2], float Z[3][3]) {
  const float eps = 5.9604645e-08f;
  const float eps2 = eps * eps;
  const float safmin = 1.17549435e-38f;
  const int nmaxit = 90;
  const int n = 3;
  int jtot = 0;
  int l1 = 0;
  while (l1 <= n - 1) {
    if (l1 > 0) e[l1 - 1] = 0.f;
    int m;
    for (m = l1; m <= n - 2; m++) {
      float tst = fabsf(e[m]);
      if (tst == 0.f) break;
      if (tst <= (sqrtf(fabsf(d[m])) * sqrtf(fabsf(d[m + 1]))) * eps) { e[m] = 0.f; break; }
    }
    int l = l1, lend = m;
    l1 = m + 1;
    if (lend == l) continue;
    if (fabsf(d[lend]) < fabsf(d[l])) { int tmp = l; l = lend; lend = tmp; }
    if (lend > l) {
      for (;;) {
        int mm = lend;
        if (l != lend) {
          for (mm = l; mm <= lend - 1; mm++) {
            float tst = e[mm] * e[mm];
            if (tst <= eps2 * fabsf(d[mm]) * fabsf(d[mm + 1]) + safmin) break;
          }
        }
        if (mm < lend) e[mm] = 0.f;
        float p = d[l];
        if (mm == l) {
          d[l] = p; l++;
          if (l <= lend) continue; else break;
        }
        if (mm == l + 1) {
          float rt1, rt2, c, s;
          slaev2f(d[l], e[l], d[l + 1], rt1, rt2, c, s);
          #pragma unroll
          for (int i = 0; i < 3; i++) {
            float tp = Z[i][l + 1];
            Z[i][l + 1] = c * tp - s * Z[i][l];
            Z[i][l] = s * tp + c * Z[i][l];
          }
          d[l] = rt1; d[l + 1] = rt2; e[l] = 0.f;
          l += 2;
          if (l <= lend) continue; else break;
        }
        if (jtot == nmaxit) break;
        jtot++;
        float g = (d[l + 1] - p) / (2.f * e[l]);
        float r = slapy2f(g, 1.f);
        g = d[mm] - p + e[l] / (g + copysignf(r, g));
        float s = 1.f, c = 1.f;
        p = 0.f;
        float cs[2], sn[2];
        for (int i = mm - 1; i >= l; i--) {
          float f = s * e[i];
          float bb = c * e[i];
          slartgf(g, f, c, s, r);
          if (i != mm - 1) e[i + 1] = r;
          g = d[i + 1] - p;
          r = (d[i] - g) * s + 2.f * c * bb;
          p = s * r;
          d[i + 1] = g + p;
          g = c * r - bb;
          cs[i] = c; sn[i] = -s;
        }
        for (int jj = mm - l - 1; jj >= 0; jj--) {
          float c_ = cs[l + jj], s_ = sn[l + jj];
          #pragma unroll
          for (int i = 0; i < 3; i++) {
            float tp = Z[i][l + jj + 1];
            Z[i][l + jj + 1] = c_ * tp - s_ * Z[i][l + jj];
            Z[i][l + jj] = s_ * tp + c_ * Z[i][l + jj];
          }
        }
        d[l] -= p;
        e[l] = g;
      }
    } else {
      for (;;) {
        int mm = lend;
        if (l != lend) {
          for (mm = l; mm >= lend + 1; mm--) {
            float tst = e[mm - 1] * e[mm - 1];
            if (tst <= eps2 * fabsf(d[mm]) * fabsf(d[mm - 1]) + safmin) break;
          }
        }
        if (mm > lend) e[mm - 1] = 0.f;
        float p = d[l];
        if (mm == l) {
          d[l] = p; l--;
          if (l >= lend) continue; else break;
        }
        if (mm == l - 1) {
          float rt1, rt2, c, s;
          slaev2f(d[l - 1], e[l - 1], d[l], rt1, rt2, c, s);
          #pragma unroll
          for (int i = 0; i < 3; i++) {
            float tp = Z[i][l];
            Z[i][l] = c * tp - s * Z[i][l - 1];
            Z[i][l - 1] = s * tp + c * Z[i][l - 1];
          }
          d[l - 1] = rt1; d[l] = rt2; e[l - 1] = 0.f;
          l -= 2;
          if (l >= lend) continue; else break;
        }
        if (jtot == nmaxit) break;
        jtot++;
        float g = (d[l - 1] - p) / (2.f * e[l - 1]);
        float r = slapy2f(g, 1.f);
        g = d[mm] - p + e[l - 1] / (g + copysignf(r, g));
        float s = 1.f, c = 1.f;
        p = 0.f;
        float cs[2], sn[2];
        for (int i = mm; i <= l - 1; i++) {
          float f = s * e[i];
          float bb = c * e[i];
          slartgf(g, f, c, s, r);
          if (i != mm) e[i - 1] = r;
          g = d[i] - p;
          r = (d[i + 1] - g) * s + 2.f * c * bb;
          p = s * r;
          d[i] = g + p;
          g = c * r - bb;
          cs[i] = c; sn[i] = s;
        }
        for (int jj = 0; jj <= l - mm - 1; jj++) {
          float c_ = cs[mm + jj], s_ = sn[mm + jj];
          #pragma unroll
          for (int i = 0; i < 3; i++) {
            float tp = Z[i][mm + jj + 1];
            Z[i][mm + jj + 1] = c_ * tp - s_ * Z[i][mm + jj];
            Z[i][mm + jj] = s_ * tp + c_ * Z[i][mm + jj];
          }
        }
        d[l] -= p;
        e[l - 1] = g;
      }
    }
  }
  for (int ii = 1; ii < 3; ii++) {
    int i = ii - 1, k = i;
    float p = d[i];
    for (int j = ii; j < 3; j++) if (d[j] < p) { k = j; p = d[j]; }
    if (k != i) {
      d[k] = d[i]; d[i] = p;
      for (int r2 = 0; r2 < 3; r2++) {
        float tp = Z[r2][i]; Z[r2][i] = Z[r2][k]; Z[r2][k] = tp;
      }
    }
  }
}

__device__ void eigh_one(float* __restrict__ ws, int id) {
  const float* st = ws + id * 16;
  float A00 = st[7], A10 = st[8], A11 = st[9], A20 = st[10], A21 = st[11], A22 = st[12];

  float d[3], e[2];
  float tau = 0.f, u2 = 0.f;
  d[0] = A00;
  float alpha = A10, x31 = A20;
  if (x31 == 0.f) {
    tau = 0.f; u2 = 0.f;
    d[1] = A11; d[2] = A22; e[0] = alpha; e[1] = A21;
  } else {
    float nrm = slapy2f(alpha, fabsf(x31));
    float beta = (alpha >= 0.f) ? -nrm : nrm;
    tau = (beta - alpha) / beta;
    u2 = (1.f / (alpha - beta)) * x31;
    float x1 = tau * (A11 + A21 * u2);
    float x2 = tau * (A21 + A22 * u2);
    float al = -0.5f * tau * (x1 + x2 * u2);
    x1 = x1 + al;
    x2 = x2 + al * u2;
    d[1] = A11 - 2.f * x1;
    e[1] = A21 - (u2 * x1 + x2);
    d[2] = A22 - 2.f * (u2 * x2);
    e[0] = beta;
  }

  float Z[3][3] = {{1.f, 0.f, 0.f}, {0.f, 1.f, 0.f}, {0.f, 0.f, 1.f}};
  steqr3(d, e, Z);

  if (tau != 0.f) {
    for (int j = 0; j < 3; j++) {
      float w = Z[1][j] + u2 * Z[2][j];
      float tw = tau * w;
      Z[1][j] -= tw;
      Z[2][j] -= tw * u2;
    }
  }
  float* fr = ws + FR_OFF + id * 9;
  for (int dd = 0; dd < 3; dd++)
    for (int ee = 0; ee < 3; ee++)
      fr[dd * 3 + ee] = Z[dd][ee];
}

// ---------------------------------------------------------------------------
// K1: merged stats (blocks 0..31) + weight-frag prep (blocks 32..74).
// stats: per-(b,g) wsum, center(3), nmean(3), Rm lower(6) -> ws[bg*16..]
// wprep: split fp32 W into (hi,lo) bf16 MFMA B-fragments at ws+WOFF_F.
//   Frag-pair p (1KB hi + 1KB lo): lane holds B[k = kt*32 + (lane>>4)*8 + i]
//   [col = nt*16 + (lane&15)], zero-padded for k >= CIN.
// ---------------------------------------------------------------------------
__global__ void prep_kernel(const float* __restrict__ pc, const float* __restrict__ nrm,
                            const float* __restrict__ drw,
                            const float* __restrict__ W1, const float* __restrict__ W2,
                            const float* __restrict__ W3, const float* __restrict__ W4,
                            const float* __restrict__ W5, float* __restrict__ ws) {
  __shared__ float red[256];
  int t = threadIdx.x;

  if (blockIdx.x < 32) {
    int bg = blockIdx.x;
    int b = bg >> 3, g = bg & 7;

    float sw = 0.f, sp0 = 0.f, sp1 = 0.f, sp2 = 0.f, sn0 = 0.f, sn1 = 0.f, sn2 = 0.f;
    for (int n = t; n < NPTS; n += 256) {
      float w = drw[((size_t)b * NPTS + n) * NG + g];
      const float* p = pc + ((size_t)b * NPTS + n) * 3;
      const float* nr = nrm + ((size_t)b * NPTS + n) * 3;
      sw += w;
      sp0 += w * p[0]; sp1 += w * p[1]; sp2 += w * p[2];
      sn0 += w * nr[0]; sn1 += w * nr[1]; sn2 += w * nr[2];
    }

    auto blockReduce = [&](float v) -> float {
      red[t] = v; __syncthreads();
      for (int s = 128; s > 0; s >>= 1) {
        if (t < s) red[t] += red[t + s];
        __syncthreads();
      }
      float r = red[0];
      __syncthreads();
      return r;
    };

    float Sw = blockReduce(sw);
    float inv = 1.f / (Sw + 1e-6f);
    float C0 = blockReduce(sp0) * inv;
    float C1 = blockReduce(sp1) * inv;
    float C2 = blockReduce(sp2) * inv;
    float M0 = blockReduce(sn0) * inv;
    float M1 = blockReduce(sn1) * inv;
    float M2 = blockReduce(sn2) * inv;

    float r00 = 0.f, r10 = 0.f, r11 = 0.f, r20 = 0.f, r21 = 0.f, r22 = 0.f;
    for (int n = t; n < NPTS; n += 256) {
      float w = drw[((size_t)b * NPTS + n) * NG + g];
      const float* p = pc + ((size_t)b * NPTS + n) * 3;
      float p0 = p[0] - C0, p1 = p[1] - C1, p2 = p[2] - C2;
      r00 += w * p0 * p0;
      r10 += w * p1 * p0;
      r11 += w * p1 * p1;
      r20 += w * p2 * p0;
      r21 += w * p2 * p1;
      r22 += w * p2 * p2;
    }
    float R00 = blockReduce(r00);
    float R10 = blockReduce(r10);
    float R11 = blockReduce(r11);
    float R20 = blockReduce(r20);
    float R21 = blockReduce(r21);
    float R22 = blockReduce(r22);

    if (t == 0) {
      float* st = ws + bg * 16;
      st[0] = Sw;
      st[1] = C0; st[2] = C1; st[3] = C2;
      st[4] = M0; st[5] = M1; st[6] = M2;
      st[7] = R00; st[8] = R10; st[9] = R11; st[10] = R20; st[11] = R21; st[12] = R22;
    }
    return;
  }

  // ---- wprep part ----
  if (t >= 64) return;
  const int FB[5] = {0, 4, 7, 15, 25};
  const int NTs[5] = {2, 3, 4, 5, 6};
  const int CINs[5] = {51, 32, 48, 64, 80};
  const int COUTs[5] = {32, 48, 64, 80, 96};
  const float* Ws[5] = {W1, W2, W3, W4, W5};

  int fp = blockIdx.x - 32;       // 0..42
  int layer = 0;
  while (layer < 4 && fp >= FB[layer + 1]) layer++;
  int rel = fp - FB[layer];
  int kt = rel / NTs[layer], nt = rel % NTs[layer];
  int lane = t;
  int c = nt * 16 + (lane & 15);
  int q = lane >> 4;
  int cin = CINs[layer], cout = COUTs[layer];
  const float* W = Ws[layer];

  unsigned short* wb = (unsigned short*)(ws + WOFF_F);
  unsigned short* dH = wb + fp * 1024 + lane * 8;
  unsigned short* dL = dH + 512;
  for (int i = 0; i < 8; i++) {
    int k = kt * 32 + q * 8 + i;
    float w = (k < cin) ? W[(size_t)k * cout + c] : 0.f;
    unsigned short hb = bf16_rne(w);
    dH[i] = hb;
    dL[i] = bf16_rne(w - bf16_f(hb));
  }
}

// ---------------------------------------------------------------------------
// K2: merged eigh (blocks 0..31, launched first so it hides under knn) +
// soft-weighted kNN (blocks 32..2079), wave-per-query, registers-only select.
// ---------------------------------------------------------------------------
__global__ __launch_bounds__(256, 4) void knn_eigh_kernel(const float* __restrict__ pc,
                                                          const float* __restrict__ drw,
                                                          int* __restrict__ idxout,
                                                          float* __restrict__ ws) {
  if (blockIdx.x < 32) {
    if (threadIdx.x == 0) eigh_one(ws, blockIdx.x);
    return;
  }
  int t = threadIdx.x;
  int lane = t & 63;
  int q = (blockIdx.x - 32) * 4 + (t >> 6);
  int b = q >> 11;
  int n = q & (NPTS - 1);

  const float* qp = pc + ((size_t)b * NPTS + n) * 3;
  float q0 = qp[0], q1 = qp[1], q2 = qp[2];
  const float4* qw4 = (const float4*)(drw + ((size_t)b * NPTS + n) * NG);
  float4 qa = qw4[0], qb = qw4[1];

  float d[32];
  #pragma unroll
  for (int j = 0; j < 32; j++) {
    int m = j * 64 + lane;
    const float4* mw4 = (const float4*)(drw + ((size_t)b * NPTS + m) * NG);
    float4 ma = mw4[0], mb = mw4[1];
    float ww = qa.x * ma.x + qa.y * ma.y + qa.z * ma.z + qa.w * ma.w
             + qb.x * mb.x + qb.y * mb.y + qb.z * mb.z + qb.w * mb.w;
    const float* mp = pc + ((size_t)b * NPTS + m) * 3;
    float dx = q0 - mp[0], dy = q1 - mp[1], dz = q2 - mp[2];
    float sq = dx * dx + dy * dy + dz * dz;
    d[j] = ww * sq + (1.f - ww) * 1000.f;
    if ((j & 3) == 3) __builtin_amdgcn_sched_barrier(0);
  }

  int myres = 0;
  #pragma unroll 1
  for (int r = 0; r < KNN_K; r++) {
    float bd = d[0];
    int bj = 0;
    #pragma unroll
    for (int j = 1; j < 32; j++) {
      if (d[j] < bd) { bd = d[j]; bj = j; }
    }
    int gm = bj * 64 + lane;
    #pragma unroll
    for (int s = 1; s < 64; s <<= 1) {
      float od = __shfl_xor(bd, s, 64);
      int om = __shfl_xor(gm, s, 64);
      if (od < bd || (od == bd && om < gm)) { bd = od; gm = om; }
    }
    if (lane == r) myres = gm;
    int ls = gm & 63, js = gm >> 6;
    if (lane == ls) {
      #pragma unroll
      for (int j = 0; j < 32; j++) {
        if (j == js) d[j] = FLOATMAX;
      }
    }
  }
  if (lane < KNN_K) idxout[(size_t)q * KNN_K + lane] = myres;
}

// ---------------------------------------------------------------------------
// K3: feature build + 5-layer MLP on the MATRIX pipe (split-bf16 MFMA).
// Block = 64 rows (8 n x 8 ops), 256 threads = 4 waves; each wave owns rows
// [wv*16, wv*16+16) of BOTH ping-pong buffers end-to-end -> NO inter-layer
// barriers (waves drift through layers independently).
// LDS = exactly 40960 B -> 4 blocks/CU (was 53760 -> 3).
//   buf0 stride 88 u16 (176B rows, 2-way bank alias = free)
//   buf1 stride 72 u16 (144B rows, 2-way)
// L5 kt=2 reads k=80..95: cols 80..87 zero-init, 88..95 overflow into the
// next row/array -- always finite, and B k>=CIN pads are zero -> contributes
// exactly 0. Array order aH0,aH1,aL0,aL1 keeps overflow in-bounds.
// ---------------------------------------------------------------------------
#define SB0 88
#define SB1 72

template <int CIN, int COUT, int FB, int SIN, int SOUT>
__device__ inline void mfma_layer(const unsigned short* __restrict__ wfr,
                                  const unsigned short* inH, const unsigned short* inL,
                                  unsigned short* outH, unsigned short* outL,
                                  const float* __restrict__ Bb, const float* __restrict__ Ss,
                                  const float* __restrict__ Oo, int lane, int wv) {
  constexpr int KT = (CIN + 31) / 32;
  constexpr int NT = COUT / 16;
  int r = lane & 15, q = lane >> 4;
  int arow = (wv * 16 + r) * SIN;

  f32x4 acc[NT];
  #pragma unroll
  for (int i = 0; i < NT; i++) acc[i] = (f32x4){0.f, 0.f, 0.f, 0.f};

  #pragma unroll
  for (int kt = 0; kt < KT; kt++) {
    bf16x8 ah = *(const bf16x8*)(inH + arow + kt * 32 + q * 8);
    bf16x8 al = *(const bf16x8*)(inL + arow + kt * 32 + q * 8);
    #pragma unroll
    for (int nt = 0; nt < NT; nt++) {
      int fid = FB + kt * NT + nt;
      bf16x8 bh = *(const bf16x8*)(wfr + fid * 1024 + lane * 8);
      bf16x8 bl = *(const bf16x8*)(wfr + fid * 1024 + 512 + lane * 8);
      acc[nt] = __builtin_amdgcn_mfma_f32_16x16x32_bf16(ah, bh, acc[nt], 0, 0, 0);
      acc[nt] = __builtin_amdgcn_mfma_f32_16x16x32_bf16(ah, bl, acc[nt], 0, 0, 0);
      acc[nt] = __builtin_amdgcn_mfma_f32_16x16x32_bf16(al, bh, acc[nt], 0, 0, 0);
    }
  }

  #pragma unroll
  for (int nt = 0; nt < NT; nt++) {
    int c = nt * 16 + r;
    float bb = Bb[c], ss = Ss[c], oo = Oo[c];
    #pragma unroll
    for (int j = 0; j < 4; j++) {
      float h = fmaxf(fmaf(acc[nt][j] + bb, ss, oo), 0.f);
      unsigned short hb = bf16_rne(h);
      int rr = (wv * 16 + q * 4 + j) * SOUT + c;
      outH[rr] = hb;
      outL[rr] = bf16_rne(h - bf16_f(hb));
    }
  }
}

__global__ __launch_bounds__(256) void mlp_kernel(
    const float* __restrict__ pc, const float* __restrict__ nrm, const float* __restrict__ drw,
    const int* __restrict__ kidx, const float* __restrict__ ws,
    const float* __restrict__ B1, const float* __restrict__ S1, const float* __restrict__ O1,
    const float* __restrict__ B2, const float* __restrict__ S2, const float* __restrict__ O2,
    const float* __restrict__ B3, const float* __restrict__ S3, const float* __restrict__ O3,
    const float* __restrict__ B4, const float* __restrict__ S4, const float* __restrict__ O4,
    const float* __restrict__ B5, const float* __restrict__ S5, const float* __restrict__ O5,
    float* __restrict__ out) {
  // 20480 u16 = 40960 B total; order matters (overflow safety): aH0,aH1,aL0,aL1
  __shared__ __align__(16) unsigned short smem[20480];
  unsigned short* aH0 = smem;            // 64*88 = 5632
  unsigned short* aH1 = smem + 5632;     // 64*72 = 4608
  unsigned short* aL0 = smem + 10240;    // 64*88
  unsigned short* aL1 = smem + 15872;    // 64*72

  int t = threadIdx.x;
  int bi = blockIdx.x;
  int b = bi >> 11;
  int g = (bi >> 8) & 7;
  int n0 = (bi & 255) << 3;
  int bg = b * 8 + g;

  // zero all act LDS (guarantees finite pad cols; weight k-pads are 0 anyway)
  {
    unsigned* z = (unsigned*)smem;
    #pragma unroll
    for (int zz = 0; zz < 40; zz++) z[zz * 256 + t] = 0u;   // 40*256*4 = 40960 B
  }
  __syncthreads();

  // ---- feature fill into buf0: base value once, 8 sign-op variants via bf16
  // sign-bit XOR (exact under RNE). f1: feat = 3*kk+e; f2: feat = 48+e.
  // Per-block scalars (frames/center/nmean/w) read directly from L2-hot ws/drw.
  if (t < 128) {
    int i = t >> 4, kk = t & 15;
    int n = n0 + i;
    int id = kidx[((size_t)b * NPTS + n) * KNN_K + kk];
    const float* p = pc + ((size_t)b * NPTS + id) * 3;
    const float* fr = ws + FR_OFF + bg * 9;
    const float* ct = ws + bg * 16 + 1;
    float w = drw[((size_t)b * NPTS + n) * NG + g];
    float v0 = w * (p[0] - ct[0]);
    float v1 = w * (p[1] - ct[1]);
    float v2 = w * (p[2] - ct[2]);
    #pragma unroll
    for (int e = 0; e < 3; e++) {
      float gv = v0 * fr[e] + v1 * fr[3 + e] + v2 * fr[6 + e];
      unsigned short hb = bf16_rne(gv);
      unsigned short lb = bf16_rne(gv - bf16_f(hb));
      int f = 3 * kk + e;
      #pragma unroll
      for (int op = 0; op < 8; op++) {
        int sb = (e == 0) ? (op >> 2) : (e == 1) ? (op >> 1) : op;
        unsigned short sgn = (unsigned short)((sb & 1) << 15);
        int rr = (i * 8 + op) * SB0 + f;
        aH0[rr] = (unsigned short)(hb ^ sgn);
        aL0[rr] = (unsigned short)(lb ^ sgn);
      }
    }
  } else if (t < 136) {
    int i = t - 128;
    int n = n0 + i;
    float w = drw[((size_t)b * NPTS + n) * NG + g];
    const float* nr = nrm + ((size_t)b * NPTS + n) * 3;
    const float* fr = ws + FR_OFF + bg * 9;
    const float* nm = ws + bg * 16 + 4;
    float v0 = nr[0] * w + (1.f - w) * nm[0];
    float v1 = nr[1] * w + (1.f - w) * nm[1];
    float v2 = nr[2] * w + (1.f - w) * nm[2];
    #pragma unroll
    for (int e = 0; e < 3; e++) {
      float gv = v0 * fr[e] + v1 * fr[3 + e] + v2 * fr[6 + e];
      unsigned short hb = bf16_rne(gv);
      unsigned short lb = bf16_rne(gv - bf16_f(hb));
      int f = 48 + e;
      #pragma unroll
      for (int op = 0; op < 8; op++) {
        int sb = (e == 0) ? (op >> 2) : (e == 1) ? (op >> 1) : op;
        unsigned short sgn = (unsigned short)((sb & 1) << 15);
        int rr = (i * 8 + op) * SB0 + f;
        aH0[rr] = (unsigned short)(hb ^ sgn);
        aL0[rr] = (unsigned short)(lb ^ sgn);
      }
    }
  }
  __syncthreads();

  const unsigned short* wfr = (const unsigned short*)(ws + WOFF_F);
  int lane = t & 63;
  int wv = t >> 6;

  // waves own disjoint 16-row slices of both buffers -> no barriers needed
  mfma_layer<51, 32, 0, SB0, SB1>(wfr, aH0, aL0, aH1, aL1, B1, S1, O1, lane, wv);
  mfma_layer<32, 48, 4, SB1, SB0>(wfr, aH1, aL1, aH0, aL0, B2, S2, O2, lane, wv);
  mfma_layer<48, 64, 7, SB0, SB1>(wfr, aH0, aL0, aH1, aL1, B3, S3, O3, lane, wv);
  mfma_layer<64, 80, 15, SB1, SB0>(wfr, aH1, aL1, aH0, aL0, B4, S4, O4, lane, wv);

  // ---- final layer 80 -> 96: MFMA then masked global store (16-lane groups
  // write 64B contiguous).
  {
    constexpr int KT = 3, NT = 6, FB = 25;
    int r = lane & 15, q = lane >> 4;
    int arow = (wv * 16 + r) * SB0;
    f32x4 acc[NT];
    #pragma unroll
    for (int i = 0; i < NT; i++) acc[i] = (f32x4){0.f, 0.f, 0.f, 0.f};
    #pragma unroll
    for (int kt = 0; kt < KT; kt++) {
      bf16x8 ah = *(const bf16x8*)(aH0 + arow + kt * 32 + q * 8);
      bf16x8 al = *(const bf16x8*)(aL0 + arow + kt * 32 + q * 8);
      #pragma unroll
      for (int nt = 0; nt < NT; nt++) {
        int fid = FB + kt * NT + nt;
        bf16x8 bh = *(const bf16x8*)(wfr + fid * 1024 + lane * 8);
        bf16x8 bl = *(const bf16x8*)(wfr + fid * 1024 + 512 + lane * 8);
        acc[nt] = __builtin_amdgcn_mfma_f32_16x16x32_bf16(ah, bh, acc[nt], 0, 0, 0);
        acc[nt] = __builtin_amdgcn_mfma_f32_16x16x32_bf16(ah, bl, acc[nt], 0, 0, 0);
        acc[nt] = __builtin_amdgcn_mfma_f32_16x16x32_bf16(al, bh, acc[nt], 0, 0, 0);
      }
    }
    // lane's 16 output rows rr = wv*16+q*4+j all share i = 2*wv + (q>>1)
    int i = 2 * wv + (q >> 1);
    int n = n0 + i;
    float wlane = drw[((size_t)b * NPTS + n) * NG + g];
    float maskv = (wlane >= 0.1f) ? 1.f : 0.f;
    int opbase = (q & 1) * 4;
    #pragma unroll
    for (int nt = 0; nt < NT; nt++) {
      int c = nt * 16 + r;
      float bb = B5[c], ss = S5[c], oo = O5[c];
      #pragma unroll
      for (int j = 0; j < 4; j++) {
        int op = opbase + j;
        float h = fmaxf(fmaf(acc[nt][j] + bb, ss, oo), 0.f);
        out[((((size_t)(b * 8 + op)) * NG + g) * NPTS + n) * 96 + c] = h * maskv;
      }
    }
  }
}

// ---------------------------------------------------------------------------
extern "C" void kernel_launch(void* const* d_in, const int* in_sizes, int n_in,
                              void* d_out, int out_size, void* d_ws, size_t ws_size,
                              hipStream_t stream) {
  const float* pc = (const float*)d_in[0];
  const float* nrm = (const float*)d_in[1];
  const float* drw = (const float*)d_in[2];
  const float* W1 = (const float*)d_in[3];
  const float* B1 = (const float*)d_in[4];
  const float* S1 = (const float*)d_in[5];
  const float* O1 = (const float*)d_in[6];
  const float* W2 = (const float*)d_in[7];
  const float* B2 = (const float*)d_in[8];
  const float* S2 = (const float*)d_in[9];
  const float* O2 = (const float*)d_in[10];
  const float* W3 = (const float*)d_in[11];
  const float* B3 = (const float*)d_in[12];
  const float* S3 = (const float*)d_in[13];
  const float* O3 = (const float*)d_in[14];
  const float* W4 = (const float*)d_in[15];
  const float* B4 = (const float*)d_in[16];
  const float* S4 = (const float*)d_in[17];
  const float* O4 = (const float*)d_in[18];
  const float* W5 = (const float*)d_in[19];
  const float* B5 = (const float*)d_in[20];
  const float* S5 = (const float*)d_in[21];
  const float* O5 = (const float*)d_in[22];
  float* out = (float*)d_out;
  float* wsf = (float*)d_ws;
  int* idxw = (int*)(wsf + IDX_OFF);

  prep_kernel<<<75, 256, 0, stream>>>(pc, nrm, drw, W1, W2, W3, W4, W5, wsf);
  knn_eigh_kernel<<<32 + BATCH * NPTS / 4, 256, 0, stream>>>(pc, drw, idxw, wsf);
  mlp_kernel<<<BATCH * NG * (NPTS / 8), 256, 0, stream>>>(
      pc, nrm, drw, idxw, wsf,
      B1, S1, O1, B2, S2, O2, B3, S3, O3,
      B4, S4, O4, B5, S5, O5, out);
}

// Round 4
// 388.212 us; speedup vs baseline: 1.1497x; 1.0023x over previous
//
#include <hip/hip_runtime.h>
#include <math.h>

#define NPTS 2048
#define BATCH 4
#define NG 8
#define KNN_K 16
#define FR_OFF 512     // floats: frames start in ws
#define IDX_OFF 1024   // floats: knn idx (as int) start in ws
#define WOFF_F (IDX_OFF + BATCH * NPTS * KNN_K)  // floats: split weight frags (132096)
#define FLOATMAX 3.402823466e38f

typedef __attribute__((ext_vector_type(8))) short bf16x8;
typedef __attribute__((ext_vector_type(4))) float f32x4;

__device__ inline unsigned short bf16_rne(float x) {
  unsigned u = __float_as_uint(x);
  u += 0x7FFFu + ((u >> 16) & 1u);
  return (unsigned short)(u >> 16);
}
__device__ inline float bf16_f(unsigned short h) {
  return __uint_as_float(((unsigned)h) << 16);
}

// pack fp32 h -> u32 (hi16 | lo16): hi = truncation (top 16 bits), lo =
// rne-bf16 of the exact remainder. hi+lo reconstructs h to ~2^-17 rel.
__device__ inline unsigned pack_hl(float h) {
  unsigned u = __float_as_uint(h);
  float rem = h - __uint_as_float(u & 0xffff0000u);
  unsigned v = __float_as_uint(rem);
  v += 0x7fffu + ((v >> 16) & 1u);
  // dst = (u.b3 u.b2 | v.b3 v.b2) = hi16<<16 | lo16
  return __builtin_amdgcn_perm(u, v, 0x07060302u);
}

// read 8 packed u32 (cols k..k+7) -> ah (8 hi bf16), al (8 lo bf16)
__device__ inline void unpack8(const unsigned* __restrict__ p, bf16x8& ah, bf16x8& al) {
  union U { unsigned u[4]; bf16x8 v; };
  uint4 x = *(const uint4*)p;
  uint4 y = *(const uint4*)(p + 4);
  U a, b;
  a.u[0] = __builtin_amdgcn_perm(x.y, x.x, 0x07060302u);
  a.u[1] = __builtin_amdgcn_perm(x.w, x.z, 0x07060302u);
  a.u[2] = __builtin_amdgcn_perm(y.y, y.x, 0x07060302u);
  a.u[3] = __builtin_amdgcn_perm(y.w, y.z, 0x07060302u);
  b.u[0] = __builtin_amdgcn_perm(x.y, x.x, 0x05040100u);
  b.u[1] = __builtin_amdgcn_perm(x.w, x.z, 0x05040100u);
  b.u[2] = __builtin_amdgcn_perm(y.y, y.x, 0x05040100u);
  b.u[3] = __builtin_amdgcn_perm(y.w, y.z, 0x05040100u);
  ah = a.v;
  al = b.v;
}

// ---------------------------------------------------------------------------
// eigh of 3x3 symmetric, LAPACK ssyevd-faithful (sytrd + steqr + ormtr)
// ---------------------------------------------------------------------------
__device__ inline float slapy2f(float x, float y) {
  float ax = fabsf(x), ay = fabsf(y);
  float w = fmaxf(ax, ay), z = fminf(ax, ay);
  if (z == 0.f) return w;
  float q = z / w;
  return w * sqrtf(1.f + q * q);
}

__device__ inline void slartgf(float f, float g, float& c, float& s, float& r) {
  if (g == 0.f) { c = 1.f; s = 0.f; r = f; }
  else if (f == 0.f) { c = 0.f; s = (g >= 0.f) ? 1.f : -1.f; r = fabsf(g); }
  else {
    float d = sqrtf(f * f + g * g);
    c = fabsf(f) / d;
    r = (f >= 0.f) ? d : -d;
    s = g / r;
  }
}

__device__ void slaev2f(float a, float b, float c, float& rt1, float& rt2, float& cs1, float& sn1) {
  float sm = a + c, df = a - c, adf = fabsf(df), tb = b + b, ab = fabsf(tb);
  float acmx, acmn;
  if (fabsf(a) > fabsf(c)) { acmx = a; acmn = c; } else { acmx = c; acmn = a; }
  float rt;
  if (adf > ab) { float t = ab / adf; rt = adf * sqrtf(1.f + t * t); }
  else if (adf < ab) { float t = adf / ab; rt = ab * sqrtf(1.f + t * t); }
  else rt = ab * sqrtf(2.f);
  int sgn1;
  if (sm < 0.f) { rt1 = 0.5f * (sm - rt); sgn1 = -1; rt2 = (acmx / rt1) * acmn - (b / rt1) * b; }
  else if (sm > 0.f) { rt1 = 0.5f * (sm + rt); sgn1 = 1; rt2 = (acmx / rt1) * acmn - (b / rt1) * b; }
  else { rt1 = 0.5f * rt; rt2 = -0.5f * rt; sgn1 = 1; }
  float cs; int sgn2;
  if (df >= 0.f) { cs = df + rt; sgn2 = 1; } else { cs = df - rt; sgn2 = -1; }
  float acs = fabsf(cs);
  if (acs > ab) {
    float ct = -tb / cs;
    sn1 = 1.f / sqrtf(1.f + ct * ct);
    cs1 = ct * sn1;
  } else {
    if (ab == 0.f) { cs1 = 1.f; sn1 = 0.f; }
    else {
      float tn = -cs / tb;
      cs1 = 1.f / sqrtf(1.f + tn * tn);
      sn1 = tn * cs1;
    }
  }
  if (sgn1 == sgn2) { float tn = cs1; cs1 = -sn1; sn1 = tn; }
}

__device__ void steqr3(float d[3], float e[2], float Z[3][3]) {
  const float eps = 5.9604645e-08f;
  const float eps2 = eps * eps;
  const float safmin = 1.17549435e-38f;
  const int nmaxit = 90;
  const int n = 3;
  int jtot = 0;
  int l1 = 0;
  while (l1 <= n - 1) {
    if (l1 > 0) e[l1 - 1] = 0.f;
    int m;
    for (m = l1; m <= n - 2; m++) {
      float tst = fabsf(e[m]);
      if (tst == 0.f) break;
      if (tst <= (sqrtf(fabsf(d[m])) * sqrtf(fabsf(d[m + 1]))) * eps) { e[m] = 0.f; break; }
    }
    int l = l1, lend = m;
    l1 = m + 1;
    if (lend == l) continue;
    if (fabsf(d[lend]) < fabsf(d[l])) { int tmp = l; l = lend; lend = tmp; }
    if (lend > l) {
      for (;;) {
        int mm = lend;
        if (l != lend) {
          for (mm = l; mm <= lend - 1; mm++) {
            float tst = e[mm] * e[mm];
            if (tst <= eps2 * fabsf(d[mm]) * fabsf(d[mm + 1]) + safmin) break;
          }
        }
        if (mm < lend) e[mm] = 0.f;
        float p = d[l];
        if (mm == l) {
          d[l] = p; l++;
          if (l <= lend) continue; else break;
        }
        if (mm == l + 1) {
          float rt1, rt2, c, s;
          slaev2f(d[l], e[l], d[l + 1], rt1, rt2, c, s);
          #pragma unroll
          for (int i = 0; i < 3; i++) {
            float tp = Z[i][l + 1];
            Z[i][l + 1] = c * tp - s * Z[i][l];
            Z[i][l] = s * tp + c * Z[i][l];
          }
          d[l] = rt1; d[l + 1] = rt2; e[l] = 0.f;
          l += 2;
          if (l <= lend) continue; else break;
        }
        if (jtot == nmaxit) break;
        jtot++;
        float g = (d[l + 1] - p) / (2.f * e[l]);
        float r = slapy2f(g, 1.f);
        g = d[mm] - p + e[l] / (g + copysignf(r, g));
        float s = 1.f, c = 1.f;
        p = 0.f;
        float cs[2], sn[2];
        for (int i = mm - 1; i >= l; i--) {
          float f = s * e[i];
          float bb = c * e[i];
          slartgf(g, f, c, s, r);
          if (i != mm - 1) e[i + 1] = r;
          g = d[i + 1] - p;
          r = (d[i] - g) * s + 2.f * c * bb;
          p = s * r;
          d[i + 1] = g + p;
          g = c * r - bb;
          cs[i] = c; sn[i] = -s;
        }
        for (int jj = mm - l - 1; jj >= 0; jj--) {
          float c_ = cs[l + jj], s_ = sn[l + jj];
          #pragma unroll
          for (int i = 0; i < 3; i++) {
            float tp = Z[i][l + jj + 1];
            Z[i][l + jj + 1] = c_ * tp - s_ * Z[i][l + jj];
            Z[i][l + jj] = s_ * tp + c_ * Z[i][l + jj];
          }
        }
        d[l] -= p;
        e[l] = g;
      }
    } else {
      for (;;) {
        int mm = lend;
        if (l != lend) {
          for (mm = l; mm >= lend + 1; mm--) {
            float tst = e[mm - 1] * e[mm - 1];
            if (tst <= eps2 * fabsf(d[mm]) * fabsf(d[mm - 1]) + safmin) break;
          }
        }
        if (mm > lend) e[mm - 1] = 0.f;
        float p = d[l];
        if (mm == l) {
          d[l] = p; l--;
          if (l >= lend) continue; else break;
        }
        if (mm == l - 1) {
          float rt1, rt2, c, s;
          slaev2f(d[l - 1], e[l - 1], d[l], rt1, rt2, c, s);
          #pragma unroll
          for (int i = 0; i < 3; i++) {
            float tp = Z[i][l];
            Z[i][l] = c * tp - s * Z[i][l - 1];
            Z[i][l - 1] = s * tp + c * Z[i][l - 1];
          }
          d[l - 1] = rt1; d[l] = rt2; e[l - 1] = 0.f;
          l -= 2;
          if (l >= lend) continue; else break;
        }
        if (jtot == nmaxit) break;
        jtot++;
        float g = (d[l - 1] - p) / (2.f * e[l - 1]);
        float r = slapy2f(g, 1.f);
        g = d[mm] - p + e[l - 1] / (g + copysignf(r, g));
        float s = 1.f, c = 1.f;
        p = 0.f;
        float cs[2], sn[2];
        for (int i = mm; i <= l - 1; i++) {
          float f = s * e[i];
          float bb = c * e[i];
          slartgf(g, f, c, s, r);
          if (i != mm) e[i - 1] = r;
          g = d[i] - p;
          r = (d[i + 1] - g) * s + 2.f * c * bb;
          p = s * r;
          d[i] = g + p;
          g = c * r - bb;
          cs[i] = c; sn[i] = s;
        }
        for (int jj = 0; jj <= l - mm - 1; jj++) {
          float c_ = cs[mm + jj], s_ = sn[mm + jj];
          #pragma unroll
          for (int i = 0; i < 3; i++) {
            float tp = Z[i][mm + jj + 1];
            Z[i][mm + jj + 1] = c_ * tp - s_ * Z[i][mm + jj];
            Z[i][mm + jj] = s_ * tp + c_ * Z[i][mm + jj];
          }
        }
        d[l] -= p;
        e[l - 1] = g;
      }
    }
  }
  for (int ii = 1; ii < 3; ii++) {
    int i = ii - 1, k = i;
    float p = d[i];
    for (int j = ii; j < 3; j++) if (d[j] < p) { k = j; p = d[j]; }
    if (k != i) {
      d[k] = d[i]; d[i] = p;
      for (int r2 = 0; r2 < 3; r2++) {
        float tp = Z[r2][i]; Z[r2][i] = Z[r2][k]; Z[r2][k] = tp;
      }
    }
  }
}

__device__ void eigh_one(float* __restrict__ ws, int id) {
  const float* st = ws + id * 16;
  float A00 = st[7], A10 = st[8], A11 = st[9], A20 = st[10], A21 = st[11], A22 = st[12];

  float d[3], e[2];
  float tau = 0.f, u2 = 0.f;
  d[0] = A00;
  float alpha = A10, x31 = A20;
  if (x31 == 0.f) {
    tau = 0.f; u2 = 0.f;
    d[1] = A11; d[2] = A22; e[0] = alpha; e[1] = A21;
  } else {
    float nrm = slapy2f(alpha, fabsf(x31));
    float beta = (alpha >= 0.f) ? -nrm : nrm;
    tau = (beta - alpha) / beta;
    u2 = (1.f / (alpha - beta)) * x31;
    float x1 = tau * (A11 + A21 * u2);
    float x2 = tau * (A21 + A22 * u2);
    float al = -0.5f * tau * (x1 + x2 * u2);
    x1 = x1 + al;
    x2 = x2 + al * u2;
    d[1] = A11 - 2.f * x1;
    e[1] = A21 - (u2 * x1 + x2);
    d[2] = A22 - 2.f * (u2 * x2);
    e[0] = beta;
  }

  float Z[3][3] = {{1.f, 0.f, 0.f}, {0.f, 1.f, 0.f}, {0.f, 0.f, 1.f}};
  steqr3(d, e, Z);

  if (tau != 0.f) {
    for (int j = 0; j < 3; j++) {
      float w = Z[1][j] + u2 * Z[2][j];
      float tw = tau * w;
      Z[1][j] -= tw;
      Z[2][j] -= tw * u2;
    }
  }
  float* fr = ws + FR_OFF + id * 9;
  for (int dd = 0; dd < 3; dd++)
    for (int ee = 0; ee < 3; ee++)
      fr[dd * 3 + ee] = Z[dd][ee];
}

// ---------------------------------------------------------------------------
// K1: merged stats (blocks 0..31) + weight-frag prep (blocks 32..74).
// ---------------------------------------------------------------------------
__global__ void prep_kernel(const float* __restrict__ pc, const float* __restrict__ nrm,
                            const float* __restrict__ drw,
                            const float* __restrict__ W1, const float* __restrict__ W2,
                            const float* __restrict__ W3, const float* __restrict__ W4,
                            const float* __restrict__ W5, float* __restrict__ ws) {
  __shared__ float red[256];
  int t = threadIdx.x;

  if (blockIdx.x < 32) {
    int bg = blockIdx.x;
    int b = bg >> 3, g = bg & 7;

    float sw = 0.f, sp0 = 0.f, sp1 = 0.f, sp2 = 0.f, sn0 = 0.f, sn1 = 0.f, sn2 = 0.f;
    for (int n = t; n < NPTS; n += 256) {
      float w = drw[((size_t)b * NPTS + n) * NG + g];
      const float* p = pc + ((size_t)b * NPTS + n) * 3;
      const float* nr = nrm + ((size_t)b * NPTS + n) * 3;
      sw += w;
      sp0 += w * p[0]; sp1 += w * p[1]; sp2 += w * p[2];
      sn0 += w * nr[0]; sn1 += w * nr[1]; sn2 += w * nr[2];
    }

    auto blockReduce = [&](float v) -> float {
      red[t] = v; __syncthreads();
      for (int s = 128; s > 0; s >>= 1) {
        if (t < s) red[t] += red[t + s];
        __syncthreads();
      }
      float r = red[0];
      __syncthreads();
      return r;
    };

    float Sw = blockReduce(sw);
    float inv = 1.f / (Sw + 1e-6f);
    float C0 = blockReduce(sp0) * inv;
    float C1 = blockReduce(sp1) * inv;
    float C2 = blockReduce(sp2) * inv;
    float M0 = blockReduce(sn0) * inv;
    float M1 = blockReduce(sn1) * inv;
    float M2 = blockReduce(sn2) * inv;

    float r00 = 0.f, r10 = 0.f, r11 = 0.f, r20 = 0.f, r21 = 0.f, r22 = 0.f;
    for (int n = t; n < NPTS; n += 256) {
      float w = drw[((size_t)b * NPTS + n) * NG + g];
      const float* p = pc + ((size_t)b * NPTS + n) * 3;
      float p0 = p[0] - C0, p1 = p[1] - C1, p2 = p[2] - C2;
      r00 += w * p0 * p0;
      r10 += w * p1 * p0;
      r11 += w * p1 * p1;
      r20 += w * p2 * p0;
      r21 += w * p2 * p1;
      r22 += w * p2 * p2;
    }
    float R00 = blockReduce(r00);
    float R10 = blockReduce(r10);
    float R11 = blockReduce(r11);
    float R20 = blockReduce(r20);
    float R21 = blockReduce(r21);
    float R22 = blockReduce(r22);

    if (t == 0) {
      float* st = ws + bg * 16;
      st[0] = Sw;
      st[1] = C0; st[2] = C1; st[3] = C2;
      st[4] = M0; st[5] = M1; st[6] = M2;
      st[7] = R00; st[8] = R10; st[9] = R11; st[10] = R20; st[11] = R21; st[12] = R22;
    }
    return;
  }

  // ---- wprep part ----
  if (t >= 64) return;
  const int FBt[5] = {0, 4, 7, 15, 25};
  const int NTs[5] = {2, 3, 4, 5, 6};
  const int CINs[5] = {51, 32, 48, 64, 80};
  const int COUTs[5] = {32, 48, 64, 80, 96};
  const float* Ws[5] = {W1, W2, W3, W4, W5};

  int fp = blockIdx.x - 32;       // 0..42
  int layer = 0;
  while (layer < 4 && fp >= FBt[layer + 1]) layer++;
  int rel = fp - FBt[layer];
  int kt = rel / NTs[layer], nt = rel % NTs[layer];
  int lane = t;
  int c = nt * 16 + (lane & 15);
  int q = lane >> 4;
  int cin = CINs[layer], cout = COUTs[layer];
  const float* W = Ws[layer];

  unsigned short* wb = (unsigned short*)(ws + WOFF_F);
  unsigned short* dH = wb + fp * 1024 + lane * 8;
  unsigned short* dL = dH + 512;
  for (int i = 0; i < 8; i++) {
    int k = kt * 32 + q * 8 + i;
    float w = (k < cin) ? W[(size_t)k * cout + c] : 0.f;
    unsigned short hb = bf16_rne(w);
    dH[i] = hb;
    dL[i] = bf16_rne(w - bf16_f(hb));
  }
}

// ---------------------------------------------------------------------------
// K2: merged eigh (blocks 0..31) + soft-weighted kNN (blocks 32..2079).
// ---------------------------------------------------------------------------
__global__ __launch_bounds__(256, 4) void knn_eigh_kernel(const float* __restrict__ pc,
                                                          const float* __restrict__ drw,
                                                          int* __restrict__ idxout,
                                                          float* __restrict__ ws) {
  if (blockIdx.x < 32) {
    if (threadIdx.x == 0) eigh_one(ws, blockIdx.x);
    return;
  }
  int t = threadIdx.x;
  int lane = t & 63;
  int q = (blockIdx.x - 32) * 4 + (t >> 6);
  int b = q >> 11;
  int n = q & (NPTS - 1);

  const float* qp = pc + ((size_t)b * NPTS + n) * 3;
  float q0 = qp[0], q1 = qp[1], q2 = qp[2];
  const float4* qw4 = (const float4*)(drw + ((size_t)b * NPTS + n) * NG);
  float4 qa = qw4[0], qb = qw4[1];

  float d[32];
  #pragma unroll
  for (int j = 0; j < 32; j++) {
    int m = j * 64 + lane;
    const float4* mw4 = (const float4*)(drw + ((size_t)b * NPTS + m) * NG);
    float4 ma = mw4[0], mb = mw4[1];
    float ww = qa.x * ma.x + qa.y * ma.y + qa.z * ma.z + qa.w * ma.w
             + qb.x * mb.x + qb.y * mb.y + qb.z * mb.z + qb.w * mb.w;
    const float* mp = pc + ((size_t)b * NPTS + m) * 3;
    float dx = q0 - mp[0], dy = q1 - mp[1], dz = q2 - mp[2];
    float sq = dx * dx + dy * dy + dz * dz;
    d[j] = ww * sq + (1.f - ww) * 1000.f;
    if ((j & 3) == 3) __builtin_amdgcn_sched_barrier(0);
  }

  int myres = 0;
  #pragma unroll 1
  for (int r = 0; r < KNN_K; r++) {
    float bd = d[0];
    int bj = 0;
    #pragma unroll
    for (int j = 1; j < 32; j++) {
      if (d[j] < bd) { bd = d[j]; bj = j; }
    }
    int gm = bj * 64 + lane;
    #pragma unroll
    for (int s = 1; s < 64; s <<= 1) {
      float od = __shfl_xor(bd, s, 64);
      int om = __shfl_xor(gm, s, 64);
      if (od < bd || (od == bd && om < gm)) { bd = od; gm = om; }
    }
    if (lane == r) myres = gm;
    int ls = gm & 63, js = gm >> 6;
    if (lane == ls) {
      #pragma unroll
      for (int j = 0; j < 32; j++) {
        if (j == js) d[j] = FLOATMAX;
      }
    }
  }
  if (lane < KNN_K) idxout[(size_t)q * KNN_K + lane] = myres;
}

// ---------------------------------------------------------------------------
// K3: feature build + 5-layer MLP on the MATRIX pipe (split-bf16 MFMA).
// Block = 64 rows (8 n x 8 ops), 4 waves; wave owns rows [wv*16, wv*16+16)
// of both ping-pong buffers -> no inter-layer barriers.
// Activations u32-PACKED (hi16|lo16) in one plane per buffer:
//   PK0 stride 84 u32 (bank cycle 8 -> 2-way, 16B-aligned rows)
//   PK1 stride 68 u32 (same properties)
// LDS = (84+68)*64*4 = 38912 B -> 4 blocks/CU.
// Epilogue: trunc-hi + rne-lo + v_perm pack + ONE ds_write_b32 per output.
// Read: 2x ds_read_b128 + 8x v_perm per A-frag pair.
// L5 reads k=80..95: cols 80..83 zeroed, 84..95 overflow into next row
// (finite; weight k>=80 pads are zero -> contributes exactly 0). Row 63
// overflow lands in PK1[0..11] (zeroed, then L1-written: always finite).
// __launch_bounds__(256,4): occupancy is LDS-capped at 4 waves/SIMD, so let
// the allocator use up to 128 VGPRs for weight-fragment load pipelining.
// NOTE: stride macros named PST0/PST1 -- S0/S1 collide with BN-scale params!
// ---------------------------------------------------------------------------
#define PST0 84
#define PST1 68

template <int CIN, int COUT, int FB, int SIN, int SOUT>
__device__ inline void mfma_layerP(const unsigned short* __restrict__ wfr,
                                   const unsigned* inP, unsigned* outP,
                                   const float* __restrict__ Bb, const float* __restrict__ Ss,
                                   const float* __restrict__ Oo, int lane, int wv) {
  constexpr int KT = (CIN + 31) / 32;
  constexpr int NT = COUT / 16;
  int r = lane & 15, q = lane >> 4;
  int arow = (wv * 16 + r) * SIN;

  f32x4 acc[NT];
  #pragma unroll
  for (int i = 0; i < NT; i++) acc[i] = (f32x4){0.f, 0.f, 0.f, 0.f};

  #pragma unroll
  for (int kt = 0; kt < KT; kt++) {
    bf16x8 ah, al;
    unpack8(inP + arow + kt * 32 + q * 8, ah, al);
    #pragma unroll
    for (int nt = 0; nt < NT; nt++) {
      int fid = FB + kt * NT + nt;
      bf16x8 bh = *(const bf16x8*)(wfr + fid * 1024 + lane * 8);
      bf16x8 bl = *(const bf16x8*)(wfr + fid * 1024 + 512 + lane * 8);
      acc[nt] = __builtin_amdgcn_mfma_f32_16x16x32_bf16(ah, bh, acc[nt], 0, 0, 0);
      acc[nt] = __builtin_amdgcn_mfma_f32_16x16x32_bf16(ah, bl, acc[nt], 0, 0, 0);
      acc[nt] = __builtin_amdgcn_mfma_f32_16x16x32_bf16(al, bh, acc[nt], 0, 0, 0);
    }
  }

  #pragma unroll
  for (int nt = 0; nt < NT; nt++) {
    int c = nt * 16 + r;
    float bb = Bb[c], ss = Ss[c], oo = Oo[c];
    #pragma unroll
    for (int j = 0; j < 4; j++) {
      float h = fmaxf(fmaf(acc[nt][j] + bb, ss, oo), 0.f);
      outP[(wv * 16 + q * 4 + j) * SOUT + c] = pack_hl(h);
    }
  }
}

__global__ __launch_bounds__(256, 4) void mlp_kernel(
    const float* __restrict__ pc, const float* __restrict__ nrm, const float* __restrict__ drw,
    const int* __restrict__ kidx, const float* __restrict__ ws,
    const float* __restrict__ B1, const float* __restrict__ S1, const float* __restrict__ O1,
    const float* __restrict__ B2, const float* __restrict__ S2, const float* __restrict__ O2,
    const float* __restrict__ B3, const float* __restrict__ S3, const float* __restrict__ O3,
    const float* __restrict__ B4, const float* __restrict__ S4, const float* __restrict__ O4,
    const float* __restrict__ B5, const float* __restrict__ S5, const float* __restrict__ O5,
    float* __restrict__ out) {
  __shared__ __align__(16) unsigned smem[9728];  // 38912 B
  unsigned* PK0 = smem;          // [64][84]
  unsigned* PK1 = smem + 5376;   // [64][68]

  int t = threadIdx.x;
  int bi = blockIdx.x;
  int b = bi >> 11;
  int g = (bi >> 8) & 7;
  int n0 = (bi & 255) << 3;
  int bg = b * 8 + g;

  // zero only never-written pad cells: PK0 cols {51..63, 80..83} x 64 rows,
  // plus PK1[0..11] (row-63 overflow target). Disjoint from feature fill.
  for (int z = t; z < 1088; z += 256) {
    int row = z / 17;
    int cc = z - row * 17;
    int col = (cc < 13) ? (51 + cc) : (67 + cc);
    PK0[row * PST0 + col] = 0u;
  }
  if (t < 12) PK1[t] = 0u;

  // ---- feature fill into PK0: base value once, 8 sign-op variants via
  // packed sign XOR (0x80008000 flips both hi and lo bf16 signs; exact).
  if (t < 128) {
    int i = t >> 4, kk = t & 15;
    int n = n0 + i;
    int id = kidx[((size_t)b * NPTS + n) * KNN_K + kk];
    const float* p = pc + ((size_t)b * NPTS + id) * 3;
    const float* fr = ws + FR_OFF + bg * 9;
    const float* ct = ws + bg * 16 + 1;
    float w = drw[((size_t)b * NPTS + n) * NG + g];
    float v0 = w * (p[0] - ct[0]);
    float v1 = w * (p[1] - ct[1]);
    float v2 = w * (p[2] - ct[2]);
    #pragma unroll
    for (int e = 0; e < 3; e++) {
      float gv = v0 * fr[e] + v1 * fr[3 + e] + v2 * fr[6 + e];
      unsigned pk = pack_hl(gv);
      int f = 3 * kk + e;
      #pragma unroll
      for (int op = 0; op < 8; op++) {
        int sb = (e == 0) ? (op >> 2) : (e == 1) ? (op >> 1) : op;
        unsigned pv = (sb & 1) ? (pk ^ 0x80008000u) : pk;
        PK0[(i * 8 + op) * PST0 + f] = pv;
      }
    }
  } else if (t < 136) {
    int i = t - 128;
    int n = n0 + i;
    float w = drw[((size_t)b * NPTS + n) * NG + g];
    const float* nr = nrm + ((size_t)b * NPTS + n) * 3;
    const float* fr = ws + FR_OFF + bg * 9;
    const float* nm = ws + bg * 16 + 4;
    float v0 = nr[0] * w + (1.f - w) * nm[0];
    float v1 = nr[1] * w + (1.f - w) * nm[1];
    float v2 = nr[2] * w + (1.f - w) * nm[2];
    #pragma unroll
    for (int e = 0; e < 3; e++) {
      float gv = v0 * fr[e] + v1 * fr[3 + e] + v2 * fr[6 + e];
      unsigned pk = pack_hl(gv);
      int f = 48 + e;
      #pragma unroll
      for (int op = 0; op < 8; op++) {
        int sb = (e == 0) ? (op >> 2) : (e == 1) ? (op >> 1) : op;
        unsigned pv = (sb & 1) ? (pk ^ 0x80008000u) : pk;
        PK0[(i * 8 + op) * PST0 + f] = pv;
      }
    }
  }
  __syncthreads();

  const unsigned short* wfr = (const unsigned short*)(ws + WOFF_F);
  int lane = t & 63;
  int wv = t >> 6;

  // waves own disjoint 16-row slices of both buffers -> no barriers needed
  mfma_layerP<51, 32, 0, PST0, PST1>(wfr, PK0, PK1, B1, S1, O1, lane, wv);
  mfma_layerP<32, 48, 4, PST1, PST0>(wfr, PK1, PK0, B2, S2, O2, lane, wv);
  mfma_layerP<48, 64, 7, PST0, PST1>(wfr, PK0, PK1, B3, S3, O3, lane, wv);
  mfma_layerP<64, 80, 15, PST1, PST0>(wfr, PK1, PK0, B4, S4, O4, lane, wv);

  // ---- final layer 80 -> 96: MFMA then masked global store (16-lane groups
  // write 64B contiguous).
  {
    constexpr int KT = 3, NT = 6, FB = 25;
    int r = lane & 15, q = lane >> 4;
    int arow = (wv * 16 + r) * PST0;
    f32x4 acc[NT];
    #pragma unroll
    for (int i = 0; i < NT; i++) acc[i] = (f32x4){0.f, 0.f, 0.f, 0.f};
    #pragma unroll
    for (int kt = 0; kt < KT; kt++) {
      bf16x8 ah, al;
      unpack8(PK0 + arow + kt * 32 + q * 8, ah, al);
      #pragma unroll
      for (int nt = 0; nt < NT; nt++) {
        int fid = FB + kt * NT + nt;
        bf16x8 bh = *(const bf16x8*)(wfr + fid * 1024 + lane * 8);
        bf16x8 bl = *(const bf16x8*)(wfr + fid * 1024 + 512 + lane * 8);
        acc[nt] = __builtin_amdgcn_mfma_f32_16x16x32_bf16(ah, bh, acc[nt], 0, 0, 0);
        acc[nt] = __builtin_amdgcn_mfma_f32_16x16x32_bf16(ah, bl, acc[nt], 0, 0, 0);
        acc[nt] = __builtin_amdgcn_mfma_f32_16x16x32_bf16(al, bh, acc[nt], 0, 0, 0);
      }
    }
    // lane's 16 output rows rr = wv*16+q*4+j all share i = 2*wv + (q>>1)
    int i = 2 * wv + (q >> 1);
    int n = n0 + i;
    float wlane = drw[((size_t)b * NPTS + n) * NG + g];
    float maskv = (wlane >= 0.1f) ? 1.f : 0.f;
    int opbase = (q & 1) * 4;
    #pragma unroll
    for (int nt = 0; nt < NT; nt++) {
      int c = nt * 16 + r;
      float bb = B5[c], ss = S5[c], oo = O5[c];
      #pragma unroll
      for (int j = 0; j < 4; j++) {
        int op = opbase + j;
        float h = fmaxf(fmaf(acc[nt][j] + bb, ss, oo), 0.f);
        out[((((size_t)(b * 8 + op)) * NG + g) * NPTS + n) * 96 + c] = h * maskv;
      }
    }
  }
}

// ---------------------------------------------------------------------------
extern "C" void kernel_launch(void* const* d_in, const int* in_sizes, int n_in,
                              void* d_out, int out_size, void* d_ws, size_t ws_size,
                              hipStream_t stream) {
  const float* pc = (const float*)d_in[0];
  const float* nrm = (const float*)d_in[1];
  const float* drw = (const float*)d_in[2];
  const float* W1 = (const float*)d_in[3];
  const float* B1 = (const float*)d_in[4];
  const float* S1 = (const float*)d_in[5];
  const float* O1 = (const float*)d_in[6];
  const float* W2 = (const float*)d_in[7];
  const float* B2 = (const float*)d_in[8];
  const float* S2 = (const float*)d_in[9];
  const float* O2 = (const float*)d_in[10];
  const float* W3 = (const float*)d_in[11];
  const float* B3 = (const float*)d_in[12];
  const float* S3 = (const float*)d_in[13];
  const float* O3 = (const float*)d_in[14];
  const float* W4 = (const float*)d_in[15];
  const float* B4 = (const float*)d_in[16];
  const float* S4 = (const float*)d_in[17];
  const float* O4 = (const float*)d_in[18];
  const float* W5 = (const float*)d_in[19];
  const float* B5 = (const float*)d_in[20];
  const float* S5 = (const float*)d_in[21];
  const float* O5 = (const float*)d_in[22];
  float* out = (float*)d_out;
  float* wsf = (float*)d_ws;
  int* idxw = (int*)(wsf + IDX_OFF);

  prep_kernel<<<75, 256, 0, stream>>>(pc, nrm, drw, W1, W2, W3, W4, W5, wsf);
  knn_eigh_kernel<<<32 + BATCH * NPTS / 4, 256, 0, stream>>>(pc, drw, idxw, wsf);
  mlp_kernel<<<BATCH * NG * (NPTS / 8), 256, 0, stream>>>(
      pc, nrm, drw, idxw, wsf,
      B1, S1, O1, B2, S2, O2, B3, S3, O3,
      B4, S4, O4, B5, S5, O5, out);
}

// Round 6
// 370.580 us; speedup vs baseline: 1.2044x; 1.0476x over previous
//
#include <hip/hip_runtime.h>
#include <math.h>

#define NPTS 2048
#define BATCH 4
#define NG 8
#define KNN_K 16
#define FR_OFF 512     // floats: frames start in ws
#define IDX_OFF 1024   // floats: knn idx (as int) start in ws
#define WOFF_F (IDX_OFF + BATCH * NPTS * KNN_K)  // floats: split weight frags
#define WOFF_B (WOFF_F + 22016)                  // floats: folded biases (320)
#define FLOATMAX 3.402823466e38f

typedef __attribute__((ext_vector_type(8))) short bf16x8;
typedef __attribute__((ext_vector_type(4))) float f32x4;

__device__ inline unsigned short bf16_rne(float x) {
  unsigned u = __float_as_uint(x);
  u += 0x7FFFu + ((u >> 16) & 1u);
  return (unsigned short)(u >> 16);
}
__device__ inline float bf16_f(unsigned short h) {
  return __uint_as_float(((unsigned)h) << 16);
}

// pack fp32 h -> u32 (hi16 | lo16): hi = truncation (top 16 bits), lo =
// rne-bf16 of the exact remainder. hi+lo reconstructs h to ~2^-17 rel.
__device__ inline unsigned pack_hl(float h) {
  unsigned u = __float_as_uint(h);
  float rem = h - __uint_as_float(u & 0xffff0000u);
  unsigned v = __float_as_uint(rem);
  v += 0x7fffu + ((v >> 16) & 1u);
  return __builtin_amdgcn_perm(u, v, 0x07060302u);
}

// read 8 packed u32 (cols k..k+7) -> ah (8 hi bf16), al (8 lo bf16)
__device__ inline void unpack8(const unsigned* __restrict__ p, bf16x8& ah, bf16x8& al) {
  union U { unsigned u[4]; bf16x8 v; };
  uint4 x = *(const uint4*)p;
  uint4 y = *(const uint4*)(p + 4);
  U a, b;
  a.u[0] = __builtin_amdgcn_perm(x.y, x.x, 0x07060302u);
  a.u[1] = __builtin_amdgcn_perm(x.w, x.z, 0x07060302u);
  a.u[2] = __builtin_amdgcn_perm(y.y, y.x, 0x07060302u);
  a.u[3] = __builtin_amdgcn_perm(y.w, y.z, 0x07060302u);
  b.u[0] = __builtin_amdgcn_perm(x.y, x.x, 0x05040100u);
  b.u[1] = __builtin_amdgcn_perm(x.w, x.z, 0x05040100u);
  b.u[2] = __builtin_amdgcn_perm(y.y, y.x, 0x05040100u);
  b.u[3] = __builtin_amdgcn_perm(y.w, y.z, 0x05040100u);
  ah = a.v;
  al = b.v;
}

// ---------------------------------------------------------------------------
// eigh of 3x3 symmetric, LAPACK ssyevd-faithful (sytrd + steqr + ormtr)
// ---------------------------------------------------------------------------
__device__ inline float slapy2f(float x, float y) {
  float ax = fabsf(x), ay = fabsf(y);
  float w = fmaxf(ax, ay), z = fminf(ax, ay);
  if (z == 0.f) return w;
  float q = z / w;
  return w * sqrtf(1.f + q * q);
}

__device__ inline void slartgf(float f, float g, float& c, float& s, float& r) {
  if (g == 0.f) { c = 1.f; s = 0.f; r = f; }
  else if (f == 0.f) { c = 0.f; s = (g >= 0.f) ? 1.f : -1.f; r = fabsf(g); }
  else {
    float d = sqrtf(f * f + g * g);
    c = fabsf(f) / d;
    r = (f >= 0.f) ? d : -d;
    s = g / r;
  }
}

__device__ void slaev2f(float a, float b, float c, float& rt1, float& rt2, float& cs1, float& sn1) {
  float sm = a + c, df = a - c, adf = fabsf(df), tb = b + b, ab = fabsf(tb);
  float acmx, acmn;
  if (fabsf(a) > fabsf(c)) { acmx = a; acmn = c; } else { acmx = c; acmn = a; }
  float rt;
  if (adf > ab) { float t = ab / adf; rt = adf * sqrtf(1.f + t * t); }
  else if (adf < ab) { float t = adf / ab; rt = ab * sqrtf(1.f + t * t); }
  else rt = ab * sqrtf(2.f);
  int sgn1;
  if (sm < 0.f) { rt1 = 0.5f * (sm - rt); sgn1 = -1; rt2 = (acmx / rt1) * acmn - (b / rt1) * b; }
  else if (sm > 0.f) { rt1 = 0.5f * (sm + rt); sgn1 = 1; rt2 = (acmx / rt1) * acmn - (b / rt1) * b; }
  else { rt1 = 0.5f * rt; rt2 = -0.5f * rt; sgn1 = 1; }
  float cs; int sgn2;
  if (df >= 0.f) { cs = df + rt; sgn2 = 1; } else { cs = df - rt; sgn2 = -1; }
  float acs = fabsf(cs);
  if (acs > ab) {
    float ct = -tb / cs;
    sn1 = 1.f / sqrtf(1.f + ct * ct);
    cs1 = ct * sn1;
  } else {
    if (ab == 0.f) { cs1 = 1.f; sn1 = 0.f; }
    else {
      float tn = -cs / tb;
      cs1 = 1.f / sqrtf(1.f + tn * tn);
      sn1 = tn * cs1;
    }
  }
  if (sgn1 == sgn2) { float tn = cs1; cs1 = -sn1; sn1 = tn; }
}

__device__ void steqr3(float d[3], float e[2], float Z[3][3]) {
  const float eps = 5.9604645e-08f;
  const float eps2 = eps * eps;
  const float safmin = 1.17549435e-38f;
  const int nmaxit = 90;
  const int n = 3;
  int jtot = 0;
  int l1 = 0;
  while (l1 <= n - 1) {
    if (l1 > 0) e[l1 - 1] = 0.f;
    int m;
    for (m = l1; m <= n - 2; m++) {
      float tst = fabsf(e[m]);
      if (tst == 0.f) break;
      if (tst <= (sqrtf(fabsf(d[m])) * sqrtf(fabsf(d[m + 1]))) * eps) { e[m] = 0.f; break; }
    }
    int l = l1, lend = m;
    l1 = m + 1;
    if (lend == l) continue;
    if (fabsf(d[lend]) < fabsf(d[l])) { int tmp = l; l = lend; lend = tmp; }
    if (lend > l) {
      for (;;) {
        int mm = lend;
        if (l != lend) {
          for (mm = l; mm <= lend - 1; mm++) {
            float tst = e[mm] * e[mm];
            if (tst <= eps2 * fabsf(d[mm]) * fabsf(d[mm + 1]) + safmin) break;
          }
        }
        if (mm < lend) e[mm] = 0.f;
        float p = d[l];
        if (mm == l) {
          d[l] = p; l++;
          if (l <= lend) continue; else break;
        }
        if (mm == l + 1) {
          float rt1, rt2, c, s;
          slaev2f(d[l], e[l], d[l + 1], rt1, rt2, c, s);
          #pragma unroll
          for (int i = 0; i < 3; i++) {
            float tp = Z[i][l + 1];
            Z[i][l + 1] = c * tp - s * Z[i][l];
            Z[i][l] = s * tp + c * Z[i][l];
          }
          d[l] = rt1; d[l + 1] = rt2; e[l] = 0.f;
          l += 2;
          if (l <= lend) continue; else break;
        }
        if (jtot == nmaxit) break;
        jtot++;
        float g = (d[l + 1] - p) / (2.f * e[l]);
        float r = slapy2f(g, 1.f);
        g = d[mm] - p + e[l] / (g + copysignf(r, g));
        float s = 1.f, c = 1.f;
        p = 0.f;
        float cs[2], sn[2];
        for (int i = mm - 1; i >= l; i--) {
          float f = s * e[i];
          float bb = c * e[i];
          slartgf(g, f, c, s, r);
          if (i != mm - 1) e[i + 1] = r;
          g = d[i + 1] - p;
          r = (d[i] - g) * s + 2.f * c * bb;
          p = s * r;
          d[i + 1] = g + p;
          g = c * r - bb;
          cs[i] = c; sn[i] = -s;
        }
        for (int jj = mm - l - 1; jj >= 0; jj--) {
          float c_ = cs[l + jj], s_ = sn[l + jj];
          #pragma unroll
          for (int i = 0; i < 3; i++) {
            float tp = Z[i][l + jj + 1];
            Z[i][l + jj + 1] = c_ * tp - s_ * Z[i][l + jj];
            Z[i][l + jj] = s_ * tp + c_ * Z[i][l + jj];
          }
        }
        d[l] -= p;
        e[l] = g;
      }
    } else {
      for (;;) {
        int mm = lend;
        if (l != lend) {
          for (mm = l; mm >= lend + 1; mm--) {
            float tst = e[mm - 1] * e[mm - 1];
            if (tst <= eps2 * fabsf(d[mm]) * fabsf(d[mm - 1]) + safmin) break;
          }
        }
        if (mm > lend) e[mm - 1] = 0.f;
        float p = d[l];
        if (mm == l) {
          d[l] = p; l--;
          if (l >= lend) continue; else break;
        }
        if (mm == l - 1) {
          float rt1, rt2, c, s;
          slaev2f(d[l - 1], e[l - 1], d[l], rt1, rt2, c, s);
          #pragma unroll
          for (int i = 0; i < 3; i++) {
            float tp = Z[i][l];
            Z[i][l] = c * tp - s * Z[i][l - 1];
            Z[i][l - 1] = s * tp + c * Z[i][l - 1];
          }
          d[l - 1] = rt1; d[l] = rt2; e[l - 1] = 0.f;
          l -= 2;
          if (l >= lend) continue; else break;
        }
        if (jtot == nmaxit) break;
        jtot++;
        float g = (d[l - 1] - p) / (2.f * e[l - 1]);
        float r = slapy2f(g, 1.f);
        g = d[mm] - p + e[l - 1] / (g + copysignf(r, g));
        float s = 1.f, c = 1.f;
        p = 0.f;
        float cs[2], sn[2];
        for (int i = mm; i <= l - 1; i++) {
          float f = s * e[i];
          float bb = c * e[i];
          slartgf(g, f, c, s, r);
          if (i != mm) e[i - 1] = r;
          g = d[i] - p;
          r = (d[i + 1] - g) * s + 2.f * c * bb;
          p = s * r;
          d[i] = g + p;
          g = c * r - bb;
          cs[i] = c; sn[i] = s;
        }
        for (int jj = 0; jj <= l - mm - 1; jj++) {
          float c_ = cs[mm + jj], s_ = sn[mm + jj];
          #pragma unroll
          for (int i = 0; i < 3; i++) {
            float tp = Z[i][mm + jj + 1];
            Z[i][mm + jj + 1] = c_ * tp - s_ * Z[i][mm + jj];
            Z[i][mm + jj] = s_ * tp + c_ * Z[i][mm + jj];
          }
        }
        d[l] -= p;
        e[l - 1] = g;
      }
    }
  }
  for (int ii = 1; ii < 3; ii++) {
    int i = ii - 1, k = i;
    float p = d[i];
    for (int j = ii; j < 3; j++) if (d[j] < p) { k = j; p = d[j]; }
    if (k != i) {
      d[k] = d[i]; d[i] = p;
      for (int r2 = 0; r2 < 3; r2++) {
        float tp = Z[r2][i]; Z[r2][i] = Z[r2][k]; Z[r2][k] = tp;
      }
    }
  }
}

// eigh from register values; writes 9-float frame
__device__ void eigh_compute(float A00, float A10, float A11, float A20, float A21,
                             float A22, float* __restrict__ fr) {
  float d[3], e[2];
  float tau = 0.f, u2 = 0.f;
  d[0] = A00;
  float alpha = A10, x31 = A20;
  if (x31 == 0.f) {
    tau = 0.f; u2 = 0.f;
    d[1] = A11; d[2] = A22; e[0] = alpha; e[1] = A21;
  } else {
    float nrm = slapy2f(alpha, fabsf(x31));
    float beta = (alpha >= 0.f) ? -nrm : nrm;
    tau = (beta - alpha) / beta;
    u2 = (1.f / (alpha - beta)) * x31;
    float x1 = tau * (A11 + A21 * u2);
    float x2 = tau * (A21 + A22 * u2);
    float al = -0.5f * tau * (x1 + x2 * u2);
    x1 = x1 + al;
    x2 = x2 + al * u2;
    d[1] = A11 - 2.f * x1;
    e[1] = A21 - (u2 * x1 + x2);
    d[2] = A22 - 2.f * (u2 * x2);
    e[0] = beta;
  }

  float Z[3][3] = {{1.f, 0.f, 0.f}, {0.f, 1.f, 0.f}, {0.f, 0.f, 1.f}};
  steqr3(d, e, Z);

  if (tau != 0.f) {
    for (int j = 0; j < 3; j++) {
      float w = Z[1][j] + u2 * Z[2][j];
      float tw = tau * w;
      Z[1][j] -= tw;
      Z[2][j] -= tw * u2;
    }
  }
  for (int dd = 0; dd < 3; dd++)
    for (int ee = 0; ee < 3; ee++)
      fr[dd * 3 + ee] = Z[dd][ee];
}

// ---------------------------------------------------------------------------
// K1 "front": blocks 0..31 = stats + fused eigh; blocks 32..74 = wprep
// (scale-folded weight frags + folded biases); blocks 75..2122 = kNN.
// All three partitions are mutually independent.
// ---------------------------------------------------------------------------
__global__ __launch_bounds__(256, 4) void front_kernel(
    const float* __restrict__ pc, const float* __restrict__ nrm,
    const float* __restrict__ drw,
    const float* __restrict__ W1, const float* __restrict__ W2,
    const float* __restrict__ W3, const float* __restrict__ W4,
    const float* __restrict__ W5,
    const float* __restrict__ B1, const float* __restrict__ S1, const float* __restrict__ O1,
    const float* __restrict__ B2, const float* __restrict__ S2, const float* __restrict__ O2,
    const float* __restrict__ B3, const float* __restrict__ S3, const float* __restrict__ O3,
    const float* __restrict__ B4, const float* __restrict__ S4, const float* __restrict__ O4,
    const float* __restrict__ B5, const float* __restrict__ S5, const float* __restrict__ O5,
    int* __restrict__ idxout, float* __restrict__ ws) {
  __shared__ float red[256];
  int t = threadIdx.x;

  if (blockIdx.x < 32) {
    // ---- stats + eigh ----
    int bg = blockIdx.x;
    int b = bg >> 3, g = bg & 7;

    float sw = 0.f, sp0 = 0.f, sp1 = 0.f, sp2 = 0.f, sn0 = 0.f, sn1 = 0.f, sn2 = 0.f;
    for (int n = t; n < NPTS; n += 256) {
      float w = drw[((size_t)b * NPTS + n) * NG + g];
      const float* p = pc + ((size_t)b * NPTS + n) * 3;
      const float* nr = nrm + ((size_t)b * NPTS + n) * 3;
      sw += w;
      sp0 += w * p[0]; sp1 += w * p[1]; sp2 += w * p[2];
      sn0 += w * nr[0]; sn1 += w * nr[1]; sn2 += w * nr[2];
    }

    auto blockReduce = [&](float v) -> float {
      red[t] = v; __syncthreads();
      for (int s = 128; s > 0; s >>= 1) {
        if (t < s) red[t] += red[t + s];
        __syncthreads();
      }
      float r = red[0];
      __syncthreads();
      return r;
    };

    float Sw = blockReduce(sw);
    float inv = 1.f / (Sw + 1e-6f);
    float C0 = blockReduce(sp0) * inv;
    float C1 = blockReduce(sp1) * inv;
    float C2 = blockReduce(sp2) * inv;
    float M0 = blockReduce(sn0) * inv;
    float M1 = blockReduce(sn1) * inv;
    float M2 = blockReduce(sn2) * inv;

    float r00 = 0.f, r10 = 0.f, r11 = 0.f, r20 = 0.f, r21 = 0.f, r22 = 0.f;
    for (int n = t; n < NPTS; n += 256) {
      float w = drw[((size_t)b * NPTS + n) * NG + g];
      const float* p = pc + ((size_t)b * NPTS + n) * 3;
      float p0 = p[0] - C0, p1 = p[1] - C1, p2 = p[2] - C2;
      r00 += w * p0 * p0;
      r10 += w * p1 * p0;
      r11 += w * p1 * p1;
      r20 += w * p2 * p0;
      r21 += w * p2 * p1;
      r22 += w * p2 * p2;
    }
    float R00 = blockReduce(r00);
    float R10 = blockReduce(r10);
    float R11 = blockReduce(r11);
    float R20 = blockReduce(r20);
    float R21 = blockReduce(r21);
    float R22 = blockReduce(r22);

    if (t == 0) {
      float* st = ws + bg * 16;
      st[1] = C0; st[2] = C1; st[3] = C2;
      st[4] = M0; st[5] = M1; st[6] = M2;
      eigh_compute(R00, R10, R11, R20, R21, R22, ws + FR_OFF + bg * 9);
    }
    return;
  }

  if (blockIdx.x < 75) {
    // ---- wprep: scale-folded split weight frags ----
    if (t >= 64) return;
    const int FBt[5] = {0, 4, 7, 15, 25};
    const int NTs[5] = {2, 3, 4, 5, 6};
    const int CINs[5] = {51, 32, 48, 64, 80};
    const int COUTs[5] = {32, 48, 64, 80, 96};
    const float* Ws[5] = {W1, W2, W3, W4, W5};
    const float* Ss[5] = {S1, S2, S3, S4, S5};

    int fp = blockIdx.x - 32;       // 0..42
    int layer = 0;
    while (layer < 4 && fp >= FBt[layer + 1]) layer++;
    int rel = fp - FBt[layer];
    int kt = rel / NTs[layer], nt = rel % NTs[layer];
    int lane = t;
    int c = nt * 16 + (lane & 15);
    int q = lane >> 4;
    int cin = CINs[layer], cout = COUTs[layer];
    const float* W = Ws[layer];
    float sc = Ss[layer][c];

    unsigned short* wb = (unsigned short*)(ws + WOFF_F);
    unsigned short* dH = wb + fp * 1024 + lane * 8;
    unsigned short* dL = dH + 512;
    for (int i = 0; i < 8; i++) {
      int k = kt * 32 + q * 8 + i;
      float w = (k < cin) ? W[(size_t)k * cout + c] * sc : 0.f;
      unsigned short hb = bf16_rne(w);
      dH[i] = hb;
      dL[i] = bf16_rne(w - bf16_f(hb));
    }

    // block fp==0 also writes folded biases: bias' = b*s + o (320 floats)
    if (fp == 0) {
      const int CUM[5] = {0, 32, 80, 144, 224};
      const float* Bs[5] = {B1, B2, B3, B4, B5};
      const float* Os[5] = {O1, O2, O3, O4, O5};
      for (int idx = t; idx < 320; idx += 64) {
        int ly = 4;
        while (ly > 0 && idx < CUM[ly]) ly--;
        int cc = idx - CUM[ly];
        ws[WOFF_B + idx] = fmaf(Bs[ly][cc], Ss[ly][cc], Os[ly][cc]);
      }
    }
    return;
  }

  // ---- kNN: wave-per-query, registers-only selection ----
  int lane = t & 63;
  int q = (blockIdx.x - 75) * 4 + (t >> 6);
  int b = q >> 11;
  int n = q & (NPTS - 1);

  const float* qp = pc + ((size_t)b * NPTS + n) * 3;
  float q0 = qp[0], q1 = qp[1], q2 = qp[2];
  const float4* qw4 = (const float4*)(drw + ((size_t)b * NPTS + n) * NG);
  float4 qa = qw4[0], qb = qw4[1];

  float d[32];
  #pragma unroll
  for (int j = 0; j < 32; j++) {
    int m = j * 64 + lane;
    const float4* mw4 = (const float4*)(drw + ((size_t)b * NPTS + m) * NG);
    float4 ma = mw4[0], mb = mw4[1];
    float ww = qa.x * ma.x + qa.y * ma.y + qa.z * ma.z + qa.w * ma.w
             + qb.x * mb.x + qb.y * mb.y + qb.z * mb.z + qb.w * mb.w;
    const float* mp = pc + ((size_t)b * NPTS + m) * 3;
    float dx = q0 - mp[0], dy = q1 - mp[1], dz = q2 - mp[2];
    float sq = dx * dx + dy * dy + dz * dz;
    d[j] = ww * sq + (1.f - ww) * 1000.f;
    if ((j & 3) == 3) __builtin_amdgcn_sched_barrier(0);
  }

  int myres = 0;
  #pragma unroll 1
  for (int r = 0; r < KNN_K; r++) {
    float bd = d[0];
    int bj = 0;
    #pragma unroll
    for (int j = 1; j < 32; j++) {
      if (d[j] < bd) { bd = d[j]; bj = j; }
    }
    int gm = bj * 64 + lane;
    #pragma unroll
    for (int s = 1; s < 64; s <<= 1) {
      float od = __shfl_xor(bd, s, 64);
      int om = __shfl_xor(gm, s, 64);
      if (od < bd || (od == bd && om < gm)) { bd = od; gm = om; }
    }
    if (lane == r) myres = gm;
    int ls = gm & 63, js = gm >> 6;
    if (lane == ls) {
      #pragma unroll
      for (int j = 0; j < 32; j++) {
        if (j == js) d[j] = FLOATMAX;
      }
    }
  }
  if (lane < KNN_K) idxout[(size_t)q * KNN_K + lane] = myres;
}

// ---------------------------------------------------------------------------
// K2: feature build + 5-layer MLP on the MATRIX pipe (split-bf16 MFMA).
// Same structure as R4 (u32-packed hi/lo activations, PST0/PST1 strides,
// 38912 B LDS -> 4 blocks/CU), PLUS:
//  - BN scale folded into weight frags at prep; bias' = b*s+o from ws.
//    Epilogue per output: add + max + pack + 1 ds_write (was +2 ops & 3 loads).
//  - raw s_barrier between layers (NO waitcnt drain -- loads stay in flight):
//    keeps the 4 waves lockstep so they share the per-layer weight-frag
//    working set in L1 (86 KB/wave L2 stream was ~63% of L2 peak).
// ---------------------------------------------------------------------------
#define PST0 84
#define PST1 68

template <int CIN, int COUT, int FB, int SIN, int SOUT>
__device__ inline void mfma_layerP(const unsigned short* __restrict__ wfr,
                                   const unsigned* inP, unsigned* outP,
                                   const float* __restrict__ bias, int lane, int wv) {
  constexpr int KT = (CIN + 31) / 32;
  constexpr int NT = COUT / 16;
  int r = lane & 15, q = lane >> 4;
  int arow = (wv * 16 + r) * SIN;

  f32x4 acc[NT];
  #pragma unroll
  for (int i = 0; i < NT; i++) acc[i] = (f32x4){0.f, 0.f, 0.f, 0.f};

  #pragma unroll
  for (int kt = 0; kt < KT; kt++) {
    bf16x8 ah, al;
    unpack8(inP + arow + kt * 32 + q * 8, ah, al);
    #pragma unroll
    for (int nt = 0; nt < NT; nt++) {
      int fid = FB + kt * NT + nt;
      bf16x8 bh = *(const bf16x8*)(wfr + fid * 1024 + lane * 8);
      bf16x8 bl = *(const bf16x8*)(wfr + fid * 1024 + 512 + lane * 8);
      acc[nt] = __builtin_amdgcn_mfma_f32_16x16x32_bf16(ah, bh, acc[nt], 0, 0, 0);
      acc[nt] = __builtin_amdgcn_mfma_f32_16x16x32_bf16(ah, bl, acc[nt], 0, 0, 0);
      acc[nt] = __builtin_amdgcn_mfma_f32_16x16x32_bf16(al, bh, acc[nt], 0, 0, 0);
    }
  }

  #pragma unroll
  for (int nt = 0; nt < NT; nt++) {
    int c = nt * 16 + r;
    float bb = bias[c];
    #pragma unroll
    for (int j = 0; j < 4; j++) {
      float h = fmaxf(acc[nt][j] + bb, 0.f);
      outP[(wv * 16 + q * 4 + j) * SOUT + c] = pack_hl(h);
    }
  }
}

__global__ __launch_bounds__(256, 4) void mlp_kernel(
    const float* __restrict__ pc, const float* __restrict__ nrm, const float* __restrict__ drw,
    const int* __restrict__ kidx, const float* __restrict__ ws,
    float* __restrict__ out) {
  __shared__ __align__(16) unsigned smem[9728];  // 38912 B
  unsigned* PK0 = smem;          // [64][84]
  unsigned* PK1 = smem + 5376;   // [64][68]

  int t = threadIdx.x;
  int bi = blockIdx.x;
  int b = bi >> 11;
  int g = (bi >> 8) & 7;
  int n0 = (bi & 255) << 3;
  int bg = b * 8 + g;

  // zero only never-written pad cells: PK0 cols {51..63, 80..83} x 64 rows,
  // plus PK1[0..11] (row-63 overflow target). Disjoint from feature fill.
  for (int z = t; z < 1088; z += 256) {
    int row = z / 17;
    int cc = z - row * 17;
    int col = (cc < 13) ? (51 + cc) : (67 + cc);
    PK0[row * PST0 + col] = 0u;
  }
  if (t < 12) PK1[t] = 0u;

  // ---- feature fill into PK0: base value once, 8 sign-op variants via
  // packed sign XOR (0x80008000 flips both hi and lo bf16 signs; exact).
  if (t < 128) {
    int i = t >> 4, kk = t & 15;
    int n = n0 + i;
    int id = kidx[((size_t)b * NPTS + n) * KNN_K + kk];
    const float* p = pc + ((size_t)b * NPTS + id) * 3;
    const float* fr = ws + FR_OFF + bg * 9;
    const float* ct = ws + bg * 16 + 1;
    float w = drw[((size_t)b * NPTS + n) * NG + g];
    float v0 = w * (p[0] - ct[0]);
    float v1 = w * (p[1] - ct[1]);
    float v2 = w * (p[2] - ct[2]);
    #pragma unroll
    for (int e = 0; e < 3; e++) {
      float gv = v0 * fr[e] + v1 * fr[3 + e] + v2 * fr[6 + e];
      unsigned pk = pack_hl(gv);
      int f = 3 * kk + e;
      #pragma unroll
      for (int op = 0; op < 8; op++) {
        int sb = (e == 0) ? (op >> 2) : (e == 1) ? (op >> 1) : op;
        unsigned pv = (sb & 1) ? (pk ^ 0x80008000u) : pk;
        PK0[(i * 8 + op) * PST0 + f] = pv;
      }
    }
  } else if (t < 136) {
    int i = t - 128;
    int n = n0 + i;
    float w = drw[((size_t)b * NPTS + n) * NG + g];
    const float* nr = nrm + ((size_t)b * NPTS + n) * 3;
    const float* fr = ws + FR_OFF + bg * 9;
    const float* nm = ws + bg * 16 + 4;
    float v0 = nr[0] * w + (1.f - w) * nm[0];
    float v1 = nr[1] * w + (1.f - w) * nm[1];
    float v2 = nr[2] * w + (1.f - w) * nm[2];
    #pragma unroll
    for (int e = 0; e < 3; e++) {
      float gv = v0 * fr[e] + v1 * fr[3 + e] + v2 * fr[6 + e];
      unsigned pk = pack_hl(gv);
      int f = 48 + e;
      #pragma unroll
      for (int op = 0; op < 8; op++) {
        int sb = (e == 0) ? (op >> 2) : (e == 1) ? (op >> 1) : op;
        unsigned pv = (sb & 1) ? (pk ^ 0x80008000u) : pk;
        PK0[(i * 8 + op) * PST0 + f] = pv;
      }
    }
  }
  __syncthreads();

  const unsigned short* wfr = (const unsigned short*)(ws + WOFF_F);
  const float* bias = ws + WOFF_B;
  int lane = t & 63;
  int wv = t >> 6;

  // waves own disjoint 16-row slices; raw s_barrier (no waitcnt) only to
  // keep waves lockstep for L1 weight-frag reuse
  mfma_layerP<51, 32, 0, PST0, PST1>(wfr, PK0, PK1, bias + 0, lane, wv);
  __builtin_amdgcn_s_barrier();
  mfma_layerP<32, 48, 4, PST1, PST0>(wfr, PK1, PK0, bias + 32, lane, wv);
  __builtin_amdgcn_s_barrier();
  mfma_layerP<48, 64, 7, PST0, PST1>(wfr, PK0, PK1, bias + 80, lane, wv);
  __builtin_amdgcn_s_barrier();
  mfma_layerP<64, 80, 15, PST1, PST0>(wfr, PK1, PK0, bias + 144, lane, wv);
  __builtin_amdgcn_s_barrier();

  // ---- final layer 80 -> 96: MFMA then masked global store ----
  {
    constexpr int KT = 3, NT = 6, FB = 25;
    int r = lane & 15, q = lane >> 4;
    int arow = (wv * 16 + r) * PST0;
    f32x4 acc[NT];
    #pragma unroll
    for (int i = 0; i < NT; i++) acc[i] = (f32x4){0.f, 0.f, 0.f, 0.f};
    #pragma unroll
    for (int kt = 0; kt < KT; kt++) {
      bf16x8 ah, al;
      unpack8(PK0 + arow + kt * 32 + q * 8, ah, al);
      #pragma unroll
      for (int nt = 0; nt < NT; nt++) {
        int fid = FB + kt * NT + nt;
        bf16x8 bh = *(const bf16x8*)(wfr + fid * 1024 + lane * 8);
        bf16x8 bl = *(const bf16x8*)(wfr + fid * 1024 + 512 + lane * 8);
        acc[nt] = __builtin_amdgcn_mfma_f32_16x16x32_bf16(ah, bh, acc[nt], 0, 0, 0);
        acc[nt] = __builtin_amdgcn_mfma_f32_16x16x32_bf16(ah, bl, acc[nt], 0, 0, 0);
        acc[nt] = __builtin_amdgcn_mfma_f32_16x16x32_bf16(al, bh, acc[nt], 0, 0, 0);
      }
    }
    // lane's 16 output rows rr = wv*16+q*4+j all share i = 2*wv + (q>>1)
    int i = 2 * wv + (q >> 1);
    int n = n0 + i;
    float wlane = drw[((size_t)b * NPTS + n) * NG + g];
    float maskv = (wlane >= 0.1f) ? 1.f : 0.f;
    int opbase = (q & 1) * 4;
    const float* b5 = ws + WOFF_B + 224;
    #pragma unroll
    for (int nt = 0; nt < NT; nt++) {
      int c = nt * 16 + r;
      float bb = b5[c];
      #pragma unroll
      for (int j = 0; j < 4; j++) {
        int op = opbase + j;
        float h = fmaxf(acc[nt][j] + bb, 0.f);
        out[((((size_t)(b * 8 + op)) * NG + g) * NPTS + n) * 96 + c] = h * maskv;
      }
    }
  }
}

// ---------------------------------------------------------------------------
extern "C" void kernel_launch(void* const* d_in, const int* in_sizes, int n_in,
                              void* d_out, int out_size, void* d_ws, size_t ws_size,
                              hipStream_t stream) {
  const float* pc = (const float*)d_in[0];
  const float* nrm = (const float*)d_in[1];
  const float* drw = (const float*)d_in[2];
  const float* W1 = (const float*)d_in[3];
  const float* B1 = (const float*)d_in[4];
  const float* S1 = (const float*)d_in[5];
  const float* O1 = (const float*)d_in[6];
  const float* W2 = (const float*)d_in[7];
  const float* B2 = (const float*)d_in[8];
  const float* S2 = (const float*)d_in[9];
  const float* O2 = (const float*)d_in[10];
  const float* W3 = (const float*)d_in[11];
  const float* B3 = (const float*)d_in[12];
  const float* S3 = (const float*)d_in[13];
  const float* O3 = (const float*)d_in[14];
  const float* W4 = (const float*)d_in[15];
  const float* B4 = (const float*)d_in[16];
  const float* S4 = (const float*)d_in[17];
  const float* O4 = (const float*)d_in[18];
  const float* W5 = (const float*)d_in[19];
  const float* B5 = (const float*)d_in[20];
  const float* S5 = (const float*)d_in[21];
  const float* O5 = (const float*)d_in[22];
  float* out = (float*)d_out;
  float* wsf = (float*)d_ws;
  int* idxw = (int*)(wsf + IDX_OFF);

  front_kernel<<<75 + BATCH * NPTS / 4, 256, 0, stream>>>(
      pc, nrm, drw, W1, W2, W3, W4, W5,
      B1, S1, O1, B2, S2, O2, B3, S3, O3, B4, S4, O4, B5, S5, O5,
      idxw, wsf);
  mlp_kernel<<<BATCH * NG * (NPTS / 8), 256, 0, stream>>>(
      pc, nrm, drw, idxw, wsf, out);
}